// Round 12
// baseline (256.664 us; speedup 1.0000x reference)
//
#include <hip/hip_runtime.h>
#include <hip/hip_bf16.h>
#include <math.h>

// Problem constants
#define BATCH 4
#define TT 4096
#define HID 512
#define NH 8
#define HD 32
#define NROW (BATCH * TT)       // 16384
#define NPAD 1152               // padded col count for 128-wide MFMA tiles
#define QSCALE 0.17677669529663687f  // 32^-0.5
#define NCHUNK 64               // chunks per (b,h); chunk length 64

// padded LDS strides (shorts): odd multiples of 8 -> conflict-free b128 rows
#define KS 40                   // for [64][32] bf16 tiles (80B rows)
#define TS 72                   // for [32][64]/[64][64] bf16 tiles (144B rows)
#define ZS 40                   // for [32][32] bf16 tiles
#define XS 36                   // f32 [64][36] X tiles (144B rows, 16B aligned)

using s16x8 = __attribute__((ext_vector_type(8))) short;
using f32x4 = __attribute__((ext_vector_type(4))) float;

#define MFMA_BF16(a, b, c) __builtin_amdgcn_mfma_f32_16x16x32_bf16((a), (b), (c), 0, 0, 0)

__device__ __forceinline__ unsigned short f2bf(float v) {
    __hip_bfloat16 h = __float2bfloat16(v);
    unsigned short u;
    __builtin_memcpy(&u, &h, 2);
    return u;
}
__device__ __forceinline__ float bf2f(unsigned short u) {
    unsigned int x = ((unsigned int)u) << 16;
    float f;
    __builtin_memcpy(&f, &x, 4);
    return f;
}
// async global->LDS, 16B per lane; LDS dest = wave-uniform base + lane*16
__device__ __forceinline__ void gload_lds16(const unsigned short* g, unsigned short* l) {
    __builtin_amdgcn_global_load_lds(
        (const __attribute__((address_space(1))) void*)g,
        (__attribute__((address_space(3))) void*)l, 16, 0, 0);
}

// ---------------------------------------------------------------------------
// cast fp32 -> bf16, 4 elements per thread
// ---------------------------------------------------------------------------
__global__ __launch_bounds__(256) void cast_bf16(
    const float* __restrict__ src, unsigned short* __restrict__ dst, int n4)
{
    int i = blockIdx.x * 256 + threadIdx.x;
    if (i >= n4) return;
    float4 v = ((const float4*)src)[i];
    ushort4 o;
    o.x = f2bf(v.x); o.y = f2bf(v.y); o.z = f2bf(v.z); o.w = f2bf(v.w);
    ((ushort4*)dst)[i] = o;
}

// ---------------------------------------------------------------------------
// concat weights into stacked bf16 [1152][512]; fold q-scale; zero pad rows
// ---------------------------------------------------------------------------
__global__ __launch_bounds__(256) void concat_w_bf(
    const float* __restrict__ Wq, const float* __restrict__ Wk,
    const float* __restrict__ Wv, const float* __restrict__ Ww,
    const float* __restrict__ Wbeta, const float* __restrict__ Wg,
    unsigned short* __restrict__ dst)
{
    int o = blockIdx.x * 256 + threadIdx.x;   // < 1152*512
    if (o >= NPAD * HID) return;
    int r = o >> 9;                           // /512
    float v;
    if      (r < 256)  v = Wq[o] * QSCALE;
    else if (r < 512)  v = Wk[o - 256 * 512];
    else if (r < 768)  v = Wv[o - 512 * 512];
    else if (r < 1024) v = Ww[o - 768 * 512];
    else if (r < 1032) v = Wbeta[o - 1024 * 512];
    else if (r < 1040) v = Wg[o - 1032 * 512];
    else               v = 0.0f;
    dst[o] = f2bf(v);
}

// ---------------------------------------------------------------------------
// Projection GEMM (bf16 MFMA): [16384,512] x [1152,512]^T.
// 3-buffer global_load_lds pipeline, counted vmcnt(4) + raw s_barrier.
// LDS XOR-swizzle (conflict-free, round 6). XCD-aware bijective remap
// (round 9: -4us). NO s_setprio (round 7: starves prefetch issue).
// ---------------------------------------------------------------------------
__global__ __launch_bounds__(256) void gemm_proj(
    const unsigned short* __restrict__ A, const unsigned short* __restrict__ B,
    unsigned short* __restrict__ qb, unsigned short* __restrict__ kb,
    unsigned short* __restrict__ vb, unsigned short* __restrict__ wbv,
    float* __restrict__ betab, float* __restrict__ gb,
    const float* __restrict__ bbeta, const float* __restrict__ bg)
{
    __shared__ __align__(16) unsigned short smem[3 * 8192];   // 49,152 B
    unsigned short* Cs = smem;            // epilogue tile [128][132], aliases staging

    const int tid = threadIdx.x;
    const int wave = tid >> 6, lane = tid & 63;
    const int quad = lane >> 4, l16 = lane & 15;
    const int wr = wave & 1, wc = wave >> 1;
    // XCD-aware remap: wid -> (xcd, idx) -> (row-block, col-block)
    const int wid = blockIdx.x;               // 0..1151
    const int xcd = wid & 7, idx = wid >> 3;  // idx 0..143
    const int rb = xcd * 16 + idx / 9;        // 0..127
    const int cb = idx % 9;                   // 0..8
    const int r0 = rb * 128;
    const int c0 = cb * 128;
    const int K = HID;
    const int NSTEP = 16;                 // K/32
    const int swz = (l16 >> 1) & 3;       // read-side XOR (row bits 1-2)

    f32x4 acc[4][4] = {};

    auto stage = [&](int k0, int b) {
        unsigned short* Ab = smem + b * 8192;
        unsigned short* Bb = Ab + 4096;
        #pragma unroll
        for (int i = 0; i < 2; ++i) {
            int slot = wave * 128 + i * 64 + lane;
            int row = slot >> 2;
            int kq = (slot & 3) ^ ((row >> 1) & 3);
            gload_lds16(&A[(size_t)(r0 + row) * K + k0 + kq * 8], &Ab[(wave * 128 + i * 64) * 8]);
            gload_lds16(&B[(size_t)(c0 + row) * K + k0 + kq * 8], &Bb[(wave * 128 + i * 64) * 8]);
        }
    };

    stage(0, 0);
    stage(32, 1);
    int cur = 0, pf = 2;
    for (int it = 0; it < NSTEP; ++it) {
        if (it < NSTEP - 1) asm volatile("s_waitcnt vmcnt(4) lgkmcnt(0)" ::: "memory");
        else                asm volatile("s_waitcnt vmcnt(0) lgkmcnt(0)" ::: "memory");
        __builtin_amdgcn_s_barrier();
        if (it + 2 < NSTEP) stage((it + 2) * 32, pf);
        const unsigned short* As = smem + cur * 8192;
        const unsigned short* Bs = As + 4096;
        s16x8 af[4], bf[4];
        #pragma unroll
        for (int mi = 0; mi < 4; ++mi)
            af[mi] = *(const s16x8*)&As[(wr * 64 + mi * 16 + l16) * 32 + (quad ^ swz) * 8];
        #pragma unroll
        for (int ni = 0; ni < 4; ++ni)
            bf[ni] = *(const s16x8*)&Bs[(wc * 64 + ni * 16 + l16) * 32 + (quad ^ swz) * 8];
        #pragma unroll
        for (int mi = 0; mi < 4; ++mi)
            #pragma unroll
            for (int ni = 0; ni < 4; ++ni)
                acc[mi][ni] = MFMA_BF16(af[mi], bf[ni], acc[mi][ni]);
        pf = cur;
        cur = (cur + 1 == 3) ? 0 : cur + 1;
    }

    if (cb < 8) {
        // ---- q/k/v/w: LDS transpose + coalesced 16B stores ----
        __syncthreads();
        #pragma unroll
        for (int mi = 0; mi < 4; ++mi)
            #pragma unroll
            for (int ni = 0; ni < 4; ++ni) {
                int col = wc * 64 + ni * 16 + l16;
                #pragma unroll
                for (int r = 0; r < 4; ++r) {
                    int row = wr * 64 + mi * 16 + quad * 4 + r;
                    Cs[row * 132 + col] = f2bf(acc[mi][ni][r]);
                }
            }
        __syncthreads();
        const int sub = cb >> 1;
        unsigned short* dst = (sub == 0) ? qb : (sub == 1) ? kb : (sub == 2) ? vb : wbv;
        const int hh0 = (cb & 1) * 4;
        const int bb = r0 >> 12, t0 = r0 & 4095;
        #pragma unroll
        for (int u = 0; u < 2; ++u) {
            int unit = tid + u * 256;          // 0..511
            int grp = unit >> 7, row = unit & 127;
            size_t gbase = ((size_t)(bb * 8 + hh0 + grp) * 4096 + t0 + row) * 32;
            #pragma unroll
            for (int i = 0; i < 4; ++i) {
                s16x8 v = *(const s16x8*)&Cs[row * 132 + grp * 32 + i * 8];
                *(s16x8*)&dst[gbase + i * 8] = v;
            }
        }
    } else {
        // ---- beta/g columns: scalar epilogue with transcendentals ----
        #pragma unroll
        for (int mi = 0; mi < 4; ++mi) {
            #pragma unroll
            for (int ni = 0; ni < 4; ++ni) {
                int col = c0 + wc * 64 + ni * 16 + l16;
                if (col >= 1040) continue;
                #pragma unroll
                for (int r = 0; r < 4; ++r) {
                    int row = r0 + wr * 64 + mi * 16 + quad * 4 + r;
                    int bb = row >> 12, t = row & 4095;
                    float v = acc[mi][ni][r];
                    if (col < 1032) {
                        float z = v + bbeta[col - 1024];
                        betab[(size_t)(bb * 8 + col - 1024) * 4096 + t] = 2.0f / (1.0f + expf(-z));
                    } else {
                        float z = v + bg[col - 1032];
                        gb[(size_t)(bb * 8 + col - 1032) * 4096 + t] =
                            fminf(z, 0.0f) - log1pf(expf(-fabsf(z)));
                    }
                }
            }
        }
    }
}

// ---------------------------------------------------------------------------
// Output GEMM (bf16 MFMA): out[16384,512] = res_bf[16384,256] @ Wo_bf[512,256]^T
// 3-buffer counted-vmcnt pipeline + LDS XOR-swizzle. K=256 -> 8 steps.
// XCD-aware bijective remap (512 = 8 x 64; 16 rb x 4 cb per XCD).
// ---------------------------------------------------------------------------
__global__ __launch_bounds__(256) void gemm_out(
    const unsigned short* __restrict__ A, const unsigned short* __restrict__ B,
    float* __restrict__ C)
{
    __shared__ __align__(16) unsigned short smem[3 * 8192];
    const int tid = threadIdx.x;
    const int wave = tid >> 6, lane = tid & 63;
    const int quad = lane >> 4, l16 = lane & 15;
    const int wr = wave & 1, wc = wave >> 1;
    const int wid = blockIdx.x;               // 0..511
    const int xcd = wid & 7, idx = wid >> 3;  // 0..63
    const int r0 = (xcd * 16 + (idx >> 2)) * 128;
    const int c0 = (idx & 3) * 128;
    const int K = 256;
    const int NSTEP = 8;
    const int swz = (l16 >> 1) & 3;

    f32x4 acc[4][4] = {};

    auto stage = [&](int k0, int b) {
        unsigned short* Ab = smem + b * 8192;
        unsigned short* Bb = Ab + 4096;
        #pragma unroll
        for (int i = 0; i < 2; ++i) {
            int slot = wave * 128 + i * 64 + lane;
            int row = slot >> 2;
            int kq = (slot & 3) ^ ((row >> 1) & 3);
            gload_lds16(&A[(size_t)(r0 + row) * K + k0 + kq * 8], &Ab[(wave * 128 + i * 64) * 8]);
            gload_lds16(&B[(size_t)(c0 + row) * K + k0 + kq * 8], &Bb[(wave * 128 + i * 64) * 8]);
        }
    };

    stage(0, 0);
    stage(32, 1);
    int cur = 0, pf = 2;
    for (int it = 0; it < NSTEP; ++it) {
        if (it < NSTEP - 1) asm volatile("s_waitcnt vmcnt(4) lgkmcnt(0)" ::: "memory");
        else                asm volatile("s_waitcnt vmcnt(0) lgkmcnt(0)" ::: "memory");
        __builtin_amdgcn_s_barrier();
        if (it + 2 < NSTEP) stage((it + 2) * 32, pf);
        const unsigned short* As = smem + cur * 8192;
        const unsigned short* Bs = As + 4096;
        s16x8 af[4], bf[4];
        #pragma unroll
        for (int mi = 0; mi < 4; ++mi)
            af[mi] = *(const s16x8*)&As[(wr * 64 + mi * 16 + l16) * 32 + (quad ^ swz) * 8];
        #pragma unroll
        for (int ni = 0; ni < 4; ++ni)
            bf[ni] = *(const s16x8*)&Bs[(wc * 64 + ni * 16 + l16) * 32 + (quad ^ swz) * 8];
        #pragma unroll
        for (int mi = 0; mi < 4; ++mi)
            #pragma unroll
            for (int ni = 0; ni < 4; ++ni)
                acc[mi][ni] = MFMA_BF16(af[mi], bf[ni], acc[mi][ni]);
        pf = cur;
        cur = (cur + 1 == 3) ? 0 : cur + 1;
    }

    #pragma unroll
    for (int mi = 0; mi < 4; ++mi)
        #pragma unroll
        for (int ni = 0; ni < 4; ++ni) {
            int col = c0 + wc * 64 + ni * 16 + l16;
            #pragma unroll
            for (int r = 0; r < 4; ++r) {
                int row = r0 + wr * 64 + mi * 16 + quad * 4 + r;
                C[(size_t)row * HID + col] = acc[mi][ni][r];
            }
        }
}

// ---------------------------------------------------------------------------
// chunk_pre: per-chunk WY precompute via MFMA. One block (256 thr) per chunk.
// Hand-pooled LDS with lifetime aliasing + packed-triangular G (round 11).
// ---------------------------------------------------------------------------
__global__ __launch_bounds__(256) void chunk_pre(
    const unsigned short* __restrict__ kb, const unsigned short* __restrict__ vb,
    unsigned short* __restrict__ wb, const float* __restrict__ betab,
    unsigned short* __restrict__ ub, unsigned short* __restrict__ rtb,
    float* __restrict__ D0buf, float* __restrict__ Pbuf)
{
    const int chunk = blockIdx.x;
    const int tid = threadIdx.x;
    const int wave = tid >> 6, lane = tid & 63;
    const int quad = lane >> 4, l16 = lane & 15;

    __shared__ __align__(16) unsigned short pool[19200];
    __shared__ __align__(16) float Gp[2016];
    __shared__ float betac[64];

    unsigned short* Kb  = pool;
    unsigned short* Vb  = pool + 2560;
    unsigned short* Wb  = pool + 5120;
    unsigned short* KT  = pool + 7680;
    unsigned short* VT  = pool + 9984;
    unsigned short* WT  = pool + 12288;
    unsigned short* Pbf = pool + 14592;
    float* XA = (float*)pool;                 // [64][XS], aliases Kb+Vb
    float* XB = (float*)(pool + 14592);       // [64][XS], aliases Pbf
    unsigned short* nUT = pool;               // [32][TS], aliases XA region
    unsigned short* nRT = pool + 2304;        // [32][TS]

    const size_t cbase = (size_t)chunk * 2048;

    {
        int row = tid >> 2, c8 = (tid & 3) * 8, o = tid * 8;
        *(s16x8*)&Kb[row * KS + c8] = *(const s16x8*)&kb[cbase + o];
        *(s16x8*)&Vb[row * KS + c8] = *(const s16x8*)&vb[cbase + o];
        // w: normalize inline. Each 4-lane group (same row) reduces ||w||^2.
        s16x8 wv = *(const s16x8*)&wb[cbase + o];
        float ss = 0.f;
        #pragma unroll
        for (int j = 0; j < 8; ++j) { float w = bf2f((unsigned short)wv[j]); ss = fmaf(w, w, ss); }
        ss += __shfl_xor(ss, 1);
        ss += __shfl_xor(ss, 2);
        float s = 1.f / (sqrtf(ss) + 1e-6f);
        s16x8 ov;
        #pragma unroll
        for (int j = 0; j < 8; ++j) ov[j] = (short)f2bf(bf2f((unsigned short)wv[j]) * s);
        *(s16x8*)&Wb[row * KS + c8] = ov;
        *(s16x8*)&wb[cbase + o] = ov;      // normalized w for chunk_out
    }
    if (tid < 64) betac[tid] = betab[(size_t)chunk * 64 + tid];
    __syncthreads();

    // transposed bf16 tiles KT/VT/WT [32][64] (stride TS); m-major lanes
    {
        int m = tid & 31, i0 = (tid >> 5) * 8;
        s16x8 a, b2, c2;
        #pragma unroll
        for (int j = 0; j < 8; ++j) {
            a[j]  = (short)Kb[(i0 + j) * KS + m];
            b2[j] = (short)Vb[(i0 + j) * KS + m];
            c2[j] = (short)Wb[(i0 + j) * KS + m];
        }
        *(s16x8*)&KT[m * TS + i0] = a;
        *(s16x8*)&VT[m * TS + i0] = b2;
        *(s16x8*)&WT[m * TS + i0] = c2;
    }
    // Gp = packed strict-tril(beta*W W^T) (f32); Pbf = strict-tril(beta*W V^T) (bf16)
    {
        s16x8 af = *(const s16x8*)&Wb[(wave * 16 + l16) * KS + quad * 8];
        #pragma unroll
        for (int jt = 0; jt < 4; ++jt) {
            s16x8 bw = *(const s16x8*)&Wb[(jt * 16 + l16) * KS + quad * 8];
            s16x8 bv = *(const s16x8*)&Vb[(jt * 16 + l16) * KS + quad * 8];
            f32x4 z = {};
            f32x4 aG = MFMA_BF16(af, bw, z);
            f32x4 aP = MFMA_BF16(af, bv, z);
            #pragma unroll
            for (int r = 0; r < 4; ++r) {
                int t = wave * 16 + quad * 4 + r;
                int j = jt * 16 + l16;
                float bt = betac[t];
                if (j < t) {
                    Gp[t * (t - 1) / 2 + j] = bt * aG[r];
                    Pbf[t * TS + j] = f2bf(bt * aP[r]);
                } else {
                    Pbf[t * TS + j] = 0;
                }
            }
        }
    }
    __syncthreads();

    // RHS: XA = beta*W ; XB = Pbf @ K (via KT). XB aliases Pbf: load frags
    // to regs, barrier, then MFMA+write.
    {
        s16x8 a0 = *(const s16x8*)&Pbf[(wave * 16 + l16) * TS + quad * 8];
        s16x8 a1 = *(const s16x8*)&Pbf[(wave * 16 + l16) * TS + 32 + quad * 8];
        s16x8 b0[2], b1[2];
        #pragma unroll
        for (int dt = 0; dt < 2; ++dt) {
            b0[dt] = *(const s16x8*)&KT[(dt * 16 + l16) * TS + quad * 8];
            b1[dt] = *(const s16x8*)&KT[(dt * 16 + l16) * TS + 32 + quad * 8];
        }
        // XA = beta*W (writes Kb+Vb region -- dead; reads Wb -- not aliased)
        {
            int r = tid >> 2, cc0 = (tid & 3) * 8;
            float bt = betac[r];
            s16x8 wv = *(const s16x8*)&Wb[r * KS + cc0];
            #pragma unroll
            for (int j = 0; j < 8; ++j) XA[r * XS + cc0 + j] = bt * bf2f((unsigned short)wv[j]);
        }
        __syncthreads();           // all Pbf reads complete before XB writes
        #pragma unroll
        for (int dt = 0; dt < 2; ++dt) {
            f32x4 z = {};
            f32x4 acc = MFMA_BF16(a0, b0[dt], z);
            acc = MFMA_BF16(a1, b1[dt], acc);
            #pragma unroll
            for (int r = 0; r < 4; ++r)
                XB[(wave * 16 + quad * 4 + r) * XS + dt * 16 + l16] = acc[r];
        }
    }

    // blocked forward substitution on XA(cols 0-31) / XB(cols 32-63)
    for (int tb = 0; tb < 64; tb += 16) {
        __syncthreads();
        if (tid < 64) {
            float* Xp = (tid < 32) ? XA : XB;
            int c = tid & 31;
            float xv[16];
            #pragma unroll
            for (int i = 0; i < 16; ++i) xv[i] = Xp[(tb + i) * XS + c];
            #pragma unroll
            for (int j = 1; j < 16; ++j) {
                int gbase = (tb + j) * (tb + j - 1) / 2 + tb;
                #pragma unroll
                for (int i = 0; i < j; ++i)
                    xv[j] = fmaf(-Gp[gbase + i], xv[i], xv[j]);
            }
            #pragma unroll
            for (int i = 1; i < 16; ++i) Xp[(tb + i) * XS + c] = xv[i];
        }
        __syncthreads();
        if (tb < 48) {
            int n4 = (48 - tb) * 16;
            for (int idx = tid; idx < n4; idx += 256) {
                int t = tb + 16 + (idx >> 4);
                int colq = idx & 15;
                float* Xp = (colq < 8) ? XA : XB;
                int cc = (colq & 7) * 4;
                int gbase = t * (t - 1) / 2 + tb;
                float4 acc = *(float4*)&Xp[t * XS + cc];
                #pragma unroll
                for (int i = 0; i < 16; ++i) {
                    float g = Gp[gbase + i];
                    float4 xs = *(const float4*)&Xp[(tb + i) * XS + cc];
                    acc.x = fmaf(-g, xs.x, acc.x);
                    acc.y = fmaf(-g, xs.y, acc.y);
                    acc.z = fmaf(-g, xs.z, acc.z);
                    acc.w = fmaf(-g, xs.w, acc.w);
                }
                *(float4*)&Xp[t * XS + cc] = acc;
            }
        }
    }
    __syncthreads();

    // write U,Rt bf16 global; reg-stage negated transposes; barrier; write
    // nUT/nRT into the XA region (all XA/XB reads complete first).
    {
        int r = tid >> 2, c8 = (tid & 3) * 8;
        s16x8 uv, rv;
        #pragma unroll
        for (int j = 0; j < 8; ++j) {
            uv[j] = (short)f2bf(XA[r * XS + c8 + j]);
            rv[j] = (short)f2bf(XB[r * XS + c8 + j]);
        }
        *(s16x8*)&ub[cbase + r * 32 + c8] = uv;
        *(s16x8*)&rtb[cbase + r * 32 + c8] = rv;
    }
    {
        int d = tid & 31, i0 = (tid >> 5) * 8;
        s16x8 u2, r2;
        #pragma unroll
        for (int j = 0; j < 8; ++j) {
            u2[j] = (short)f2bf(-XA[(i0 + j) * XS + d]);
            r2[j] = (short)f2bf(-XB[(i0 + j) * XS + d]);
        }
        __syncthreads();           // all XA/XB reads done before overwrite
        *(s16x8*)&nUT[d * TS + i0] = u2;
        *(s16x8*)&nRT[d * TS + i0] = r2;
    }
    __syncthreads();

    // D0 = V^T K - W^T Rt ; Pmat = I - W^T U   (one 16x16 tile per wave)
    {
        int mt = wave >> 1, nt = wave & 1;
        s16x8 va0 = *(const s16x8*)&VT[(mt * 16 + l16) * TS + quad * 8];
        s16x8 va1 = *(const s16x8*)&VT[(mt * 16 + l16) * TS + 32 + quad * 8];
        s16x8 wa0 = *(const s16x8*)&WT[(mt * 16 + l16) * TS + quad * 8];
        s16x8 wa1 = *(const s16x8*)&WT[(mt * 16 + l16) * TS + 32 + quad * 8];
        s16x8 kb0 = *(const s16x8*)&KT[(nt * 16 + l16) * TS + quad * 8];
        s16x8 kb1 = *(const s16x8*)&KT[(nt * 16 + l16) * TS + 32 + quad * 8];
        s16x8 rb0 = *(const s16x8*)&nRT[(nt * 16 + l16) * TS + quad * 8];
        s16x8 rb1 = *(const s16x8*)&nRT[(nt * 16 + l16) * TS + 32 + quad * 8];
        s16x8 ub0 = *(const s16x8*)&nUT[(nt * 16 + l16) * TS + quad * 8];
        s16x8 ub1 = *(const s16x8*)&nUT[(nt * 16 + l16) * TS + 32 + quad * 8];
        f32x4 z = {};
        f32x4 d0 = MFMA_BF16(va0, kb0, z);
        d0 = MFMA_BF16(va1, kb1, d0);
        d0 = MFMA_BF16(wa0, rb0, d0);
        d0 = MFMA_BF16(wa1, rb1, d0);
        f32x4 pm = MFMA_BF16(wa0, ub0, z);
        pm = MFMA_BF16(wa1, ub1, pm);
        int m0 = mt * 16 + quad * 4, dd = nt * 16 + l16;
        #pragma unroll
        for (int r = 0; r < 4; ++r) {
            D0buf[(size_t)chunk * 1024 + (m0 + r) * 32 + dd] = d0[r];
            Pbuf[(size_t)chunk * 1024 + (m0 + r) * 32 + dd] =
                pm[r] + ((m0 + r) == dd ? 1.f : 0.f);
        }
    }
}

// ---------------------------------------------------------------------------
// scan_states: per (b,h), sequential scan over 64 chunks (fp32).
// BARRIER-FREE: columns of Z are independent under Z_new = P Z_old + D0,
// so each wave owns an 8-column slice with a private Zs[wave][32][8].
// Wave-lockstep (CDNA wave64) + one lgkmcnt(0) after publish = correct:
// old-state reads complete before zcur=acc (data dep), which precedes the
// next publish (program order). P duplication drops 8x -> 2x.
// ---------------------------------------------------------------------------
__global__ __launch_bounds__(256) void scan_states(
    const float* __restrict__ Pbuf, const float* __restrict__ D0buf,
    float* __restrict__ Z0buf)
{
    const int bh = blockIdx.x;
    const int tid = threadIdx.x;
    const int wave = tid >> 6, lane = tid & 63;
    const int m = lane >> 1;               // 0..31
    const int jloc = (lane & 1) * 4;       // local col base within wave's 8
    const int j0 = wave * 8 + jloc;        // global col base
    __shared__ __align__(16) float Zs[4][32][8];

    float4 zcur = make_float4(0.f, 0.f, 0.f, 0.f);

    size_t cb = (size_t)bh * 64 * 1024;
    // prefetch chunk 0: full P row m (32 f), D0 quad
    float4 pn[8];
    #pragma unroll
    for (int i = 0; i < 8; ++i)
        pn[i] = *(const float4*)&Pbuf[cb + m * 32 + i * 4];
    float4 dn = *(const float4*)&D0buf[cb + m * 32 + j0];

    for (int c = 0; c < NCHUNK; ++c) {
        float4 pc[8];
        #pragma unroll
        for (int i = 0; i < 8; ++i) pc[i] = pn[i];
        float4 dc = dn;
        size_t cbn = cb + 1024;
        if (c + 1 < NCHUNK) {
            #pragma unroll
            for (int i = 0; i < 8; ++i)
                pn[i] = *(const float4*)&Pbuf[cbn + m * 32 + i * 4];
            dn = *(const float4*)&D0buf[cbn + m * 32 + j0];
        }
        // Z0 (state BEFORE chunk c)
        *(float4*)&Z0buf[cb + m * 32 + j0] = zcur;

        // publish current state; wave-synchronous visibility
        *(float4*)&Zs[wave][m][jloc] = zcur;
        asm volatile("s_waitcnt lgkmcnt(0)" ::: "memory");

        // znew[m][j0..] = sum_mp P[m][mp] * Z[mp][j0..] + D0
        float4 acc = dc;
        #pragma unroll
        for (int i = 0; i < 8; ++i) {
            float pv[4] = {pc[i].x, pc[i].y, pc[i].z, pc[i].w};
            #pragma unroll
            for (int t = 0; t < 4; ++t) {
                float4 zr = *(const float4*)&Zs[wave][i * 4 + t][jloc];
                acc.x = fmaf(pv[t], zr.x, acc.x);
                acc.y = fmaf(pv[t], zr.y, acc.y);
                acc.z = fmaf(pv[t], zr.z, acc.z);
                acc.w = fmaf(pv[t], zr.w, acc.w);
            }
        }
        zcur = acc;
        cb = cbn;
    }
}

// ---------------------------------------------------------------------------
// chunk_out: O = (QZ0^T + tril(QK^T)V - tril(Q(Rt+UZ0)^T)W) * exp(g), bf16 out
// LDS tiles padded (KS/TS/ZS). A1m/nA2m ALIAS the Vb/Wb/Ub/Rb pool (all dead
// before the A1 phase writes): 50,432 B => 3 blocks/CU.
// ---------------------------------------------------------------------------
__global__ __launch_bounds__(256) void chunk_out(
    const unsigned short* __restrict__ qb, const unsigned short* __restrict__ kb,
    const unsigned short* __restrict__ vb, const unsigned short* __restrict__ wb,
    const unsigned short* __restrict__ ub, const unsigned short* __restrict__ rtb,
    const float* __restrict__ Z0buf, const float* __restrict__ gb,
    unsigned short* __restrict__ res_bf)
{
    const int chunk = blockIdx.x;
    const int bh = chunk >> 6, c = chunk & 63;
    const int b = bh >> 3, h = bh & 7;
    const int row0 = b * TT + c * 64;
    const int tid = threadIdx.x;
    const int wave = tid >> 6, lane = tid & 63;
    const int quad = lane >> 4, l16 = lane & 15;

    __shared__ __align__(16) unsigned short Qb[64 * KS], Kb[64 * KS], S2[64 * KS];
    // pool: Vb/Wb/Ub/Rb live until S2 phase; A1m/nA2m written after the
    // barrier that follows -> disjoint lifetimes, alias the same storage.
    __shared__ __align__(16) unsigned short pool[4 * 64 * KS];   // 20,480 B
    unsigned short* Vb = pool;
    unsigned short* Wb = pool + 64 * KS;
    unsigned short* Ub = pool + 2 * 64 * KS;
    unsigned short* Rb = pool + 3 * 64 * KS;
    unsigned short* A1m  = pool;                 // 64*TS shorts
    unsigned short* nA2m = pool + 64 * TS;       // 64*TS shorts (18,432 B total)
    __shared__ __align__(16) unsigned short VT[32 * TS], WT[32 * TS];
    __shared__ __align__(16) unsigned short Z0b[32 * ZS], Z0T[32 * ZS];
    __shared__ float gc[64];

    const size_t cbase = (size_t)chunk * 2048;
    {
        int row = tid >> 2, c8 = (tid & 3) * 8, o = tid * 8;
        *(s16x8*)&Qb[row * KS + c8] = *(const s16x8*)&qb[cbase + o];
        *(s16x8*)&Kb[row * KS + c8] = *(const s16x8*)&kb[cbase + o];
        *(s16x8*)&Vb[row * KS + c8] = *(const s16x8*)&vb[cbase + o];
        *(s16x8*)&Wb[row * KS + c8] = *(const s16x8*)&wb[cbase + o];
        *(s16x8*)&Ub[row * KS + c8] = *(const s16x8*)&ub[cbase + o];
        *(s16x8*)&Rb[row * KS + c8] = *(const s16x8*)&rtb[cbase + o];
    }
    {
        #pragma unroll
        for (int j = 0; j < 4; ++j) {
            int e = tid * 4 + j;
            float z = Z0buf[(size_t)chunk * 1024 + e];
            unsigned short zb = f2bf(z);
            Z0b[(e >> 5) * ZS + (e & 31)] = zb;
            Z0T[(e & 31) * ZS + (e >> 5)] = zb;
        }
    }
    if (tid < 64) gc[tid] = gb[(size_t)chunk * 64 + tid];
    __syncthreads();

    // transposes VT/WT [32][64] (stride TS); m-major lanes
    {
        int m = tid & 31, i0 = (tid >> 5) * 8;
        s16x8 a, b2;
        #pragma unroll
        for (int j = 0; j < 8; ++j) {
            a[j]  = (short)Vb[(i0 + j) * KS + m];
            b2[j] = (short)Wb[(i0 + j) * KS + m];
        }
        *(s16x8*)&VT[m * TS + i0] = a;
        *(s16x8*)&WT[m * TS + i0] = b2;
    }
    // S2 = Rt + U Z0
    {
        s16x8 af = *(const s16x8*)&Ub[(wave * 16 + l16) * KS + quad * 8];
        #pragma unroll
        for (int dt = 0; dt < 2; ++dt) {
            s16x8 bf_ = *(const s16x8*)&Z0T[(dt * 16 + l16) * ZS + quad * 8];
            f32x4 z = {};
            f32x4 acc = MFMA_BF16(af, bf_, z);
            #pragma unroll
            for (int r = 0; r < 4; ++r) {
                int j = wave * 16 + quad * 4 + r;
                int d = dt * 16 + l16;
                float s2 = acc[r] + bf2f(Rb[j * KS + d]);
                S2[j * KS + d] = f2bf(s2);
            }
        }
    }
    __syncthreads();     // Vb/Wb/Ub/Rb dead past this point -> pool reusable

    // A1 = tril(QK^T), nA2 = -tril(Q S2^T)   (inclusive diag)
    {
        s16x8 qf = *(const s16x8*)&Qb[(wave * 16 + l16) * KS + quad * 8];
        #pragma unroll
        for (int jt = 0; jt < 4; ++jt) {
            s16x8 kf = *(const s16x8*)&Kb[(jt * 16 + l16) * KS + quad * 8];
            s16x8 sf = *(const s16x8*)&S2[(jt * 16 + l16) * KS + quad * 8];
            f32x4 z = {};
            f32x4 a1 = MFMA_BF16(qf, kf, z);
            f32x4 a2 = MFMA_BF16(qf, sf, z);
            #pragma unroll
            for (int r = 0; r < 4; ++r) {
                int t = wave * 16 + quad * 4 + r;
                int j = jt * 16 + l16;
                bool keep = (j <= t);
                A1m[t * TS + j]  = keep ? f2bf(a1[r]) : (unsigned short)0;
                nA2m[t * TS + j] = keep ? f2bf(-a2[r]) : (unsigned short)0;
            }
        }
    }
    __syncthreads();

    // O = Q Z0^T + A1m V + nA2m W ; scale exp(g); store bf16
    {
        s16x8 qf = *(const s16x8*)&Qb[(wave * 16 + l16) * KS + quad * 8];
        s16x8 p0 = *(const s16x8*)&A1m[(wave * 16 + l16) * TS + quad * 8];
        s16x8 p1 = *(const s16x8*)&A1m[(wave * 16 + l16) * TS + 32 + quad * 8];
        s16x8 m0 = *(const s16x8*)&nA2m[(wave * 16 + l16) * TS + quad * 8];
        s16x8 m1 = *(const s16x8*)&nA2m[(wave * 16 + l16) * TS + 32 + quad * 8];
        #pragma unroll
        for (int mt = 0; mt < 2; ++mt) {
            s16x8 zf = *(const s16x8*)&Z0b[(mt * 16 + l16) * ZS + quad * 8];
            s16x8 v0 = *(const s16x8*)&VT[(mt * 16 + l16) * TS + quad * 8];
            s16x8 v1 = *(const s16x8*)&VT[(mt * 16 + l16) * TS + 32 + quad * 8];
            s16x8 w0 = *(const s16x8*)&WT[(mt * 16 + l16) * TS + quad * 8];
            s16x8 w1 = *(const s16x8*)&WT[(mt * 16 + l16) * TS + 32 + quad * 8];
            f32x4 z = {};
            f32x4 acc = MFMA_BF16(qf, zf, z);
            acc = MFMA_BF16(p0, v0, acc);
            acc = MFMA_BF16(p1, v1, acc);
            acc = MFMA_BF16(m0, w0, acc);
            acc = MFMA_BF16(m1, w1, acc);
            #pragma unroll
            for (int r = 0; r < 4; ++r) {
                int t = wave * 16 + quad * 4 + r;
                int m = mt * 16 + l16;
                float e = expf(gc[t]);
                res_bf[(size_t)(row0 + t) * 256 + h * 32 + m] = f2bf(acc[r] * e);
            }
        }
    }
}

// ---------------------------------------------------------------------------
extern "C" void kernel_launch(void* const* d_in, const int* in_sizes, int n_in,
                              void* d_out, int out_size, void* d_ws, size_t ws_size,
                              hipStream_t stream)
{
    const float* x     = (const float*)d_in[0];
    const float* Wq    = (const float*)d_in[1];
    const float* Wk    = (const float*)d_in[2];
    const float* Wv    = (const float*)d_in[3];
    const float* Ww    = (const float*)d_in[4];
    const float* Wbeta = (const float*)d_in[5];
    const float* bbeta = (const float*)d_in[6];
    const float* Wg    = (const float*)d_in[7];
    const float* bg    = (const float*)d_in[8];
    const float* Wo    = (const float*)d_in[9];
    float* out = (float*)d_out;

    unsigned short* x_bf       = (unsigned short*)d_ws;           // 8,388,608
    unsigned short* stacked_bf = x_bf + (size_t)NROW * HID;       // 589,824
    unsigned short* Wo_bf      = stacked_bf + (size_t)NPAD * HID; // 131,072
    unsigned short* qb  = Wo_bf + (size_t)HID * 256;              // 4,194,304 each
    unsigned short* kb  = qb + (size_t)NROW * 256;
    unsigned short* vb  = kb + (size_t)NROW * 256;
    unsigned short* wbv = vb + (size_t)NROW * 256;
    unsigned short* ub  = wbv + (size_t)NROW * 256;
    unsigned short* rtb = ub + (size_t)NROW * 256;
    unsigned short* res_bf = rtb + (size_t)NROW * 256;
    float* betab = (float*)(res_bf + (size_t)NROW * 256);         // 131,072 f
    float* gb    = betab + (size_t)NROW * 8;
    float* D0buf = gb + (size_t)NROW * 8;                         // 2,097,152 f each
    float* Pbuf  = D0buf + (size_t)2048 * 1024;
    float* Z0buf = Pbuf + (size_t)2048 * 1024;

    // 1. casts + weight concat
    cast_bf16<<<(NROW * HID / 4 + 255) / 256, 256, 0, stream>>>(x, x_bf, NROW * HID / 4);
    cast_bf16<<<(HID * 256 / 4 + 255) / 256, 256, 0, stream>>>(Wo, Wo_bf, HID * 256 / 4);
    concat_w_bf<<<(NPAD * HID + 255) / 256, 256, 0, stream>>>(Wq, Wk, Wv, Ww, Wbeta, Wg, stacked_bf);

    // 2. projection GEMM -> head-major bf16 q/k/v/w + fp32 beta/g
    //    (1-D grid, XCD-aware bijective remap inside the kernel)
    gemm_proj<<<NROW / 128 * (NPAD / 128), 256, 0, stream>>>(
        x_bf, stacked_bf, qb, kb, vb, wbv, betab, gb, bbeta, bg);

    // 3. chunked delta-rule precompute (MFMA, pooled LDS -> 3 blocks/CU)
    chunk_pre<<<2048, 256, 0, stream>>>(kb, vb, wbv, betab, ub, rtb, D0buf, Pbuf);

    // 4. chunk-state scan (barrier-free per-wave column slices)
    scan_states<<<32, 256, 0, stream>>>(Pbuf, D0buf, Z0buf);

    // 5. Z-dependent output terms (MFMA, writes bf16 res)
    chunk_out<<<2048, 256, 0, stream>>>(qb, kb, vb, wbv, ub, rtb, Z0buf, gb, res_bf);

    // 6. output GEMM: out = res @ Wo^T (1-D grid, XCD remap inside)
    gemm_out<<<512, 256, 0, stream>>>(res_bf, Wo_bf, out);
}

// Round 13
// 249.146 us; speedup vs baseline: 1.0302x; 1.0302x over previous
//
#include <hip/hip_runtime.h>
#include <hip/hip_bf16.h>
#include <math.h>

// Problem constants
#define BATCH 4
#define TT 4096
#define HID 512
#define NH 8
#define HD 32
#define NROW (BATCH * TT)       // 16384
#define NPAD 1152               // padded col count for 128-wide MFMA tiles
#define QSCALE 0.17677669529663687f  // 32^-0.5
#define NCHUNK 64               // chunks per (b,h); chunk length 64

// padded LDS strides (shorts): odd multiples of 8 -> conflict-free b128 rows
#define KS 40                   // for [64][32] bf16 tiles (80B rows)
#define TS 72                   // for [32][64]/[64][64] bf16 tiles (144B rows)
#define ZS 40                   // for [32][32] bf16 tiles
#define XS 36                   // f32 [64][36] X tiles (144B rows, 16B aligned)

using s16x8 = __attribute__((ext_vector_type(8))) short;
using f32x4 = __attribute__((ext_vector_type(4))) float;

#define MFMA_BF16(a, b, c) __builtin_amdgcn_mfma_f32_16x16x32_bf16((a), (b), (c), 0, 0, 0)

__device__ __forceinline__ unsigned short f2bf(float v) {
    __hip_bfloat16 h = __float2bfloat16(v);
    unsigned short u;
    __builtin_memcpy(&u, &h, 2);
    return u;
}
__device__ __forceinline__ float bf2f(unsigned short u) {
    unsigned int x = ((unsigned int)u) << 16;
    float f;
    __builtin_memcpy(&f, &x, 4);
    return f;
}
// async global->LDS, 16B per lane; LDS dest = wave-uniform base + lane*16
__device__ __forceinline__ void gload_lds16(const unsigned short* g, unsigned short* l) {
    __builtin_amdgcn_global_load_lds(
        (const __attribute__((address_space(1))) void*)g,
        (__attribute__((address_space(3))) void*)l, 16, 0, 0);
}

// ---------------------------------------------------------------------------
// cast fp32 -> bf16, 4 elements per thread
// ---------------------------------------------------------------------------
__global__ __launch_bounds__(256) void cast_bf16(
    const float* __restrict__ src, unsigned short* __restrict__ dst, int n4)
{
    int i = blockIdx.x * 256 + threadIdx.x;
    if (i >= n4) return;
    float4 v = ((const float4*)src)[i];
    ushort4 o;
    o.x = f2bf(v.x); o.y = f2bf(v.y); o.z = f2bf(v.z); o.w = f2bf(v.w);
    ((ushort4*)dst)[i] = o;
}

// ---------------------------------------------------------------------------
// concat weights into stacked bf16 [1152][512]; fold q-scale; zero pad rows
// ---------------------------------------------------------------------------
__global__ __launch_bounds__(256) void concat_w_bf(
    const float* __restrict__ Wq, const float* __restrict__ Wk,
    const float* __restrict__ Wv, const float* __restrict__ Ww,
    const float* __restrict__ Wbeta, const float* __restrict__ Wg,
    unsigned short* __restrict__ dst)
{
    int o = blockIdx.x * 256 + threadIdx.x;   // < 1152*512
    if (o >= NPAD * HID) return;
    int r = o >> 9;                           // /512
    float v;
    if      (r < 256)  v = Wq[o] * QSCALE;
    else if (r < 512)  v = Wk[o - 256 * 512];
    else if (r < 768)  v = Wv[o - 512 * 512];
    else if (r < 1024) v = Ww[o - 768 * 512];
    else if (r < 1032) v = Wbeta[o - 1024 * 512];
    else if (r < 1040) v = Wg[o - 1032 * 512];
    else               v = 0.0f;
    dst[o] = f2bf(v);
}

// ---------------------------------------------------------------------------
// Projection GEMM (bf16 MFMA): [16384,512] x [1152,512]^T.
// 3-buffer global_load_lds pipeline, counted vmcnt(4) + raw s_barrier.
// LDS XOR-swizzle (conflict-free, round 6). XCD-aware bijective remap
// (round 9: -4us). NO s_setprio (round 7: starves prefetch issue).
// ---------------------------------------------------------------------------
__global__ __launch_bounds__(256) void gemm_proj(
    const unsigned short* __restrict__ A, const unsigned short* __restrict__ B,
    unsigned short* __restrict__ qb, unsigned short* __restrict__ kb,
    unsigned short* __restrict__ vb, unsigned short* __restrict__ wbv,
    float* __restrict__ betab, float* __restrict__ gb,
    const float* __restrict__ bbeta, const float* __restrict__ bg)
{
    __shared__ __align__(16) unsigned short smem[3 * 8192];   // 49,152 B
    unsigned short* Cs = smem;            // epilogue tile [128][132], aliases staging

    const int tid = threadIdx.x;
    const int wave = tid >> 6, lane = tid & 63;
    const int quad = lane >> 4, l16 = lane & 15;
    const int wr = wave & 1, wc = wave >> 1;
    // XCD-aware remap: wid -> (xcd, idx) -> (row-block, col-block)
    const int wid = blockIdx.x;               // 0..1151
    const int xcd = wid & 7, idx = wid >> 3;  // idx 0..143
    const int rb = xcd * 16 + idx / 9;        // 0..127
    const int cb = idx % 9;                   // 0..8
    const int r0 = rb * 128;
    const int c0 = cb * 128;
    const int K = HID;
    const int NSTEP = 16;                 // K/32
    const int swz = (l16 >> 1) & 3;       // read-side XOR (row bits 1-2)

    f32x4 acc[4][4] = {};

    auto stage = [&](int k0, int b) {
        unsigned short* Ab = smem + b * 8192;
        unsigned short* Bb = Ab + 4096;
        #pragma unroll
        for (int i = 0; i < 2; ++i) {
            int slot = wave * 128 + i * 64 + lane;
            int row = slot >> 2;
            int kq = (slot & 3) ^ ((row >> 1) & 3);
            gload_lds16(&A[(size_t)(r0 + row) * K + k0 + kq * 8], &Ab[(wave * 128 + i * 64) * 8]);
            gload_lds16(&B[(size_t)(c0 + row) * K + k0 + kq * 8], &Bb[(wave * 128 + i * 64) * 8]);
        }
    };

    stage(0, 0);
    stage(32, 1);
    int cur = 0, pf = 2;
    for (int it = 0; it < NSTEP; ++it) {
        if (it < NSTEP - 1) asm volatile("s_waitcnt vmcnt(4) lgkmcnt(0)" ::: "memory");
        else                asm volatile("s_waitcnt vmcnt(0) lgkmcnt(0)" ::: "memory");
        __builtin_amdgcn_s_barrier();
        if (it + 2 < NSTEP) stage((it + 2) * 32, pf);
        const unsigned short* As = smem + cur * 8192;
        const unsigned short* Bs = As + 4096;
        s16x8 af[4], bf[4];
        #pragma unroll
        for (int mi = 0; mi < 4; ++mi)
            af[mi] = *(const s16x8*)&As[(wr * 64 + mi * 16 + l16) * 32 + (quad ^ swz) * 8];
        #pragma unroll
        for (int ni = 0; ni < 4; ++ni)
            bf[ni] = *(const s16x8*)&Bs[(wc * 64 + ni * 16 + l16) * 32 + (quad ^ swz) * 8];
        #pragma unroll
        for (int mi = 0; mi < 4; ++mi)
            #pragma unroll
            for (int ni = 0; ni < 4; ++ni)
                acc[mi][ni] = MFMA_BF16(af[mi], bf[ni], acc[mi][ni]);
        pf = cur;
        cur = (cur + 1 == 3) ? 0 : cur + 1;
    }

    if (cb < 8) {
        // ---- q/k/v/w: LDS transpose + coalesced 16B stores ----
        __syncthreads();
        #pragma unroll
        for (int mi = 0; mi < 4; ++mi)
            #pragma unroll
            for (int ni = 0; ni < 4; ++ni) {
                int col = wc * 64 + ni * 16 + l16;
                #pragma unroll
                for (int r = 0; r < 4; ++r) {
                    int row = wr * 64 + mi * 16 + quad * 4 + r;
                    Cs[row * 132 + col] = f2bf(acc[mi][ni][r]);
                }
            }
        __syncthreads();
        const int sub = cb >> 1;
        unsigned short* dst = (sub == 0) ? qb : (sub == 1) ? kb : (sub == 2) ? vb : wbv;
        const int hh0 = (cb & 1) * 4;
        const int bb = r0 >> 12, t0 = r0 & 4095;
        #pragma unroll
        for (int u = 0; u < 2; ++u) {
            int unit = tid + u * 256;          // 0..511
            int grp = unit >> 7, row = unit & 127;
            size_t gbase = ((size_t)(bb * 8 + hh0 + grp) * 4096 + t0 + row) * 32;
            #pragma unroll
            for (int i = 0; i < 4; ++i) {
                s16x8 v = *(const s16x8*)&Cs[row * 132 + grp * 32 + i * 8];
                *(s16x8*)&dst[gbase + i * 8] = v;
            }
        }
    } else {
        // ---- beta/g columns: scalar epilogue with transcendentals ----
        #pragma unroll
        for (int mi = 0; mi < 4; ++mi) {
            #pragma unroll
            for (int ni = 0; ni < 4; ++ni) {
                int col = c0 + wc * 64 + ni * 16 + l16;
                if (col >= 1040) continue;
                #pragma unroll
                for (int r = 0; r < 4; ++r) {
                    int row = r0 + wr * 64 + mi * 16 + quad * 4 + r;
                    int bb = row >> 12, t = row & 4095;
                    float v = acc[mi][ni][r];
                    if (col < 1032) {
                        float z = v + bbeta[col - 1024];
                        betab[(size_t)(bb * 8 + col - 1024) * 4096 + t] = 2.0f / (1.0f + expf(-z));
                    } else {
                        float z = v + bg[col - 1032];
                        gb[(size_t)(bb * 8 + col - 1032) * 4096 + t] =
                            fminf(z, 0.0f) - log1pf(expf(-fabsf(z)));
                    }
                }
            }
        }
    }
}

// ---------------------------------------------------------------------------
// Output GEMM (bf16 MFMA): out[16384,512] = res_bf[16384,256] @ Wo_bf[512,256]^T
// 3-buffer counted-vmcnt pipeline + LDS XOR-swizzle. K=256 -> 8 steps.
// 2-D grid (round 13: XCD remap reverted -- suspected cross-iteration cache
// interaction with gemm_proj; A/B attribution).
// ---------------------------------------------------------------------------
__global__ __launch_bounds__(256) void gemm_out(
    const unsigned short* __restrict__ A, const unsigned short* __restrict__ B,
    float* __restrict__ C)
{
    __shared__ __align__(16) unsigned short smem[3 * 8192];
    const int tid = threadIdx.x;
    const int wave = tid >> 6, lane = tid & 63;
    const int quad = lane >> 4, l16 = lane & 15;
    const int wr = wave & 1, wc = wave >> 1;
    const int r0 = blockIdx.x * 128;
    const int c0 = blockIdx.y * 128;
    const int K = 256;
    const int NSTEP = 8;
    const int swz = (l16 >> 1) & 3;

    f32x4 acc[4][4] = {};

    auto stage = [&](int k0, int b) {
        unsigned short* Ab = smem + b * 8192;
        unsigned short* Bb = Ab + 4096;
        #pragma unroll
        for (int i = 0; i < 2; ++i) {
            int slot = wave * 128 + i * 64 + lane;
            int row = slot >> 2;
            int kq = (slot & 3) ^ ((row >> 1) & 3);
            gload_lds16(&A[(size_t)(r0 + row) * K + k0 + kq * 8], &Ab[(wave * 128 + i * 64) * 8]);
            gload_lds16(&B[(size_t)(c0 + row) * K + k0 + kq * 8], &Bb[(wave * 128 + i * 64) * 8]);
        }
    };

    stage(0, 0);
    stage(32, 1);
    int cur = 0, pf = 2;
    for (int it = 0; it < NSTEP; ++it) {
        if (it < NSTEP - 1) asm volatile("s_waitcnt vmcnt(4) lgkmcnt(0)" ::: "memory");
        else                asm volatile("s_waitcnt vmcnt(0) lgkmcnt(0)" ::: "memory");
        __builtin_amdgcn_s_barrier();
        if (it + 2 < NSTEP) stage((it + 2) * 32, pf);
        const unsigned short* As = smem + cur * 8192;
        const unsigned short* Bs = As + 4096;
        s16x8 af[4], bf[4];
        #pragma unroll
        for (int mi = 0; mi < 4; ++mi)
            af[mi] = *(const s16x8*)&As[(wr * 64 + mi * 16 + l16) * 32 + (quad ^ swz) * 8];
        #pragma unroll
        for (int ni = 0; ni < 4; ++ni)
            bf[ni] = *(const s16x8*)&Bs[(wc * 64 + ni * 16 + l16) * 32 + (quad ^ swz) * 8];
        #pragma unroll
        for (int mi = 0; mi < 4; ++mi)
            #pragma unroll
            for (int ni = 0; ni < 4; ++ni)
                acc[mi][ni] = MFMA_BF16(af[mi], bf[ni], acc[mi][ni]);
        pf = cur;
        cur = (cur + 1 == 3) ? 0 : cur + 1;
    }

    #pragma unroll
    for (int mi = 0; mi < 4; ++mi)
        #pragma unroll
        for (int ni = 0; ni < 4; ++ni) {
            int col = c0 + wc * 64 + ni * 16 + l16;
            #pragma unroll
            for (int r = 0; r < 4; ++r) {
                int row = r0 + wr * 64 + mi * 16 + quad * 4 + r;
                C[(size_t)row * HID + col] = acc[mi][ni][r];
            }
        }
}

// ---------------------------------------------------------------------------
// chunk_pre: per-chunk WY precompute via MFMA. One block (256 thr) per chunk.
// Hand-pooled LDS with lifetime aliasing + packed-triangular G (round 11).
// ---------------------------------------------------------------------------
__global__ __launch_bounds__(256) void chunk_pre(
    const unsigned short* __restrict__ kb, const unsigned short* __restrict__ vb,
    unsigned short* __restrict__ wb, const float* __restrict__ betab,
    unsigned short* __restrict__ ub, unsigned short* __restrict__ rtb,
    float* __restrict__ D0buf, float* __restrict__ Pbuf)
{
    const int chunk = blockIdx.x;
    const int tid = threadIdx.x;
    const int wave = tid >> 6, lane = tid & 63;
    const int quad = lane >> 4, l16 = lane & 15;

    __shared__ __align__(16) unsigned short pool[19200];
    __shared__ __align__(16) float Gp[2016];
    __shared__ float betac[64];

    unsigned short* Kb  = pool;
    unsigned short* Vb  = pool + 2560;
    unsigned short* Wb  = pool + 5120;
    unsigned short* KT  = pool + 7680;
    unsigned short* VT  = pool + 9984;
    unsigned short* WT  = pool + 12288;
    unsigned short* Pbf = pool + 14592;
    float* XA = (float*)pool;                 // [64][XS], aliases Kb+Vb
    float* XB = (float*)(pool + 14592);       // [64][XS], aliases Pbf
    unsigned short* nUT = pool;               // [32][TS], aliases XA region
    unsigned short* nRT = pool + 2304;        // [32][TS]

    const size_t cbase = (size_t)chunk * 2048;

    {
        int row = tid >> 2, c8 = (tid & 3) * 8, o = tid * 8;
        *(s16x8*)&Kb[row * KS + c8] = *(const s16x8*)&kb[cbase + o];
        *(s16x8*)&Vb[row * KS + c8] = *(const s16x8*)&vb[cbase + o];
        // w: normalize inline. Each 4-lane group (same row) reduces ||w||^2.
        s16x8 wv = *(const s16x8*)&wb[cbase + o];
        float ss = 0.f;
        #pragma unroll
        for (int j = 0; j < 8; ++j) { float w = bf2f((unsigned short)wv[j]); ss = fmaf(w, w, ss); }
        ss += __shfl_xor(ss, 1);
        ss += __shfl_xor(ss, 2);
        float s = 1.f / (sqrtf(ss) + 1e-6f);
        s16x8 ov;
        #pragma unroll
        for (int j = 0; j < 8; ++j) ov[j] = (short)f2bf(bf2f((unsigned short)wv[j]) * s);
        *(s16x8*)&Wb[row * KS + c8] = ov;
        *(s16x8*)&wb[cbase + o] = ov;      // normalized w for chunk_out
    }
    if (tid < 64) betac[tid] = betab[(size_t)chunk * 64 + tid];
    __syncthreads();

    // transposed bf16 tiles KT/VT/WT [32][64] (stride TS); m-major lanes
    {
        int m = tid & 31, i0 = (tid >> 5) * 8;
        s16x8 a, b2, c2;
        #pragma unroll
        for (int j = 0; j < 8; ++j) {
            a[j]  = (short)Kb[(i0 + j) * KS + m];
            b2[j] = (short)Vb[(i0 + j) * KS + m];
            c2[j] = (short)Wb[(i0 + j) * KS + m];
        }
        *(s16x8*)&KT[m * TS + i0] = a;
        *(s16x8*)&VT[m * TS + i0] = b2;
        *(s16x8*)&WT[m * TS + i0] = c2;
    }
    // Gp = packed strict-tril(beta*W W^T) (f32); Pbf = strict-tril(beta*W V^T) (bf16)
    {
        s16x8 af = *(const s16x8*)&Wb[(wave * 16 + l16) * KS + quad * 8];
        #pragma unroll
        for (int jt = 0; jt < 4; ++jt) {
            s16x8 bw = *(const s16x8*)&Wb[(jt * 16 + l16) * KS + quad * 8];
            s16x8 bv = *(const s16x8*)&Vb[(jt * 16 + l16) * KS + quad * 8];
            f32x4 z = {};
            f32x4 aG = MFMA_BF16(af, bw, z);
            f32x4 aP = MFMA_BF16(af, bv, z);
            #pragma unroll
            for (int r = 0; r < 4; ++r) {
                int t = wave * 16 + quad * 4 + r;
                int j = jt * 16 + l16;
                float bt = betac[t];
                if (j < t) {
                    Gp[t * (t - 1) / 2 + j] = bt * aG[r];
                    Pbf[t * TS + j] = f2bf(bt * aP[r]);
                } else {
                    Pbf[t * TS + j] = 0;
                }
            }
        }
    }
    __syncthreads();

    // RHS: XA = beta*W ; XB = Pbf @ K (via KT). XB aliases Pbf: load frags
    // to regs, barrier, then MFMA+write.
    {
        s16x8 a0 = *(const s16x8*)&Pbf[(wave * 16 + l16) * TS + quad * 8];
        s16x8 a1 = *(const s16x8*)&Pbf[(wave * 16 + l16) * TS + 32 + quad * 8];
        s16x8 b0[2], b1[2];
        #pragma unroll
        for (int dt = 0; dt < 2; ++dt) {
            b0[dt] = *(const s16x8*)&KT[(dt * 16 + l16) * TS + quad * 8];
            b1[dt] = *(const s16x8*)&KT[(dt * 16 + l16) * TS + 32 + quad * 8];
        }
        // XA = beta*W (writes Kb+Vb region -- dead; reads Wb -- not aliased)
        {
            int r = tid >> 2, cc0 = (tid & 3) * 8;
            float bt = betac[r];
            s16x8 wv = *(const s16x8*)&Wb[r * KS + cc0];
            #pragma unroll
            for (int j = 0; j < 8; ++j) XA[r * XS + cc0 + j] = bt * bf2f((unsigned short)wv[j]);
        }
        __syncthreads();           // all Pbf reads complete before XB writes
        #pragma unroll
        for (int dt = 0; dt < 2; ++dt) {
            f32x4 z = {};
            f32x4 acc = MFMA_BF16(a0, b0[dt], z);
            acc = MFMA_BF16(a1, b1[dt], acc);
            #pragma unroll
            for (int r = 0; r < 4; ++r)
                XB[(wave * 16 + quad * 4 + r) * XS + dt * 16 + l16] = acc[r];
        }
    }

    // blocked forward substitution on XA(cols 0-31) / XB(cols 32-63)
    for (int tb = 0; tb < 64; tb += 16) {
        __syncthreads();
        if (tid < 64) {
            float* Xp = (tid < 32) ? XA : XB;
            int c = tid & 31;
            float xv[16];
            #pragma unroll
            for (int i = 0; i < 16; ++i) xv[i] = Xp[(tb + i) * XS + c];
            #pragma unroll
            for (int j = 1; j < 16; ++j) {
                int gbase = (tb + j) * (tb + j - 1) / 2 + tb;
                #pragma unroll
                for (int i = 0; i < j; ++i)
                    xv[j] = fmaf(-Gp[gbase + i], xv[i], xv[j]);
            }
            #pragma unroll
            for (int i = 1; i < 16; ++i) Xp[(tb + i) * XS + c] = xv[i];
        }
        __syncthreads();
        if (tb < 48) {
            int n4 = (48 - tb) * 16;
            for (int idx = tid; idx < n4; idx += 256) {
                int t = tb + 16 + (idx >> 4);
                int colq = idx & 15;
                float* Xp = (colq < 8) ? XA : XB;
                int cc = (colq & 7) * 4;
                int gbase = t * (t - 1) / 2 + tb;
                float4 acc = *(float4*)&Xp[t * XS + cc];
                #pragma unroll
                for (int i = 0; i < 16; ++i) {
                    float g = Gp[gbase + i];
                    float4 xs = *(const float4*)&Xp[(tb + i) * XS + cc];
                    acc.x = fmaf(-g, xs.x, acc.x);
                    acc.y = fmaf(-g, xs.y, acc.y);
                    acc.z = fmaf(-g, xs.z, acc.z);
                    acc.w = fmaf(-g, xs.w, acc.w);
                }
                *(float4*)&Xp[t * XS + cc] = acc;
            }
        }
    }
    __syncthreads();

    // write U,Rt bf16 global; reg-stage negated transposes; barrier; write
    // nUT/nRT into the XA region (all XA/XB reads complete first).
    {
        int r = tid >> 2, c8 = (tid & 3) * 8;
        s16x8 uv, rv;
        #pragma unroll
        for (int j = 0; j < 8; ++j) {
            uv[j] = (short)f2bf(XA[r * XS + c8 + j]);
            rv[j] = (short)f2bf(XB[r * XS + c8 + j]);
        }
        *(s16x8*)&ub[cbase + r * 32 + c8] = uv;
        *(s16x8*)&rtb[cbase + r * 32 + c8] = rv;
    }
    {
        int d = tid & 31, i0 = (tid >> 5) * 8;
        s16x8 u2, r2;
        #pragma unroll
        for (int j = 0; j < 8; ++j) {
            u2[j] = (short)f2bf(-XA[(i0 + j) * XS + d]);
            r2[j] = (short)f2bf(-XB[(i0 + j) * XS + d]);
        }
        __syncthreads();           // all XA/XB reads done before overwrite
        *(s16x8*)&nUT[d * TS + i0] = u2;
        *(s16x8*)&nRT[d * TS + i0] = r2;
    }
    __syncthreads();

    // D0 = V^T K - W^T Rt ; Pmat = I - W^T U   (one 16x16 tile per wave)
    {
        int mt = wave >> 1, nt = wave & 1;
        s16x8 va0 = *(const s16x8*)&VT[(mt * 16 + l16) * TS + quad * 8];
        s16x8 va1 = *(const s16x8*)&VT[(mt * 16 + l16) * TS + 32 + quad * 8];
        s16x8 wa0 = *(const s16x8*)&WT[(mt * 16 + l16) * TS + quad * 8];
        s16x8 wa1 = *(const s16x8*)&WT[(mt * 16 + l16) * TS + 32 + quad * 8];
        s16x8 kb0 = *(const s16x8*)&KT[(nt * 16 + l16) * TS + quad * 8];
        s16x8 kb1 = *(const s16x8*)&KT[(nt * 16 + l16) * TS + 32 + quad * 8];
        s16x8 rb0 = *(const s16x8*)&nRT[(nt * 16 + l16) * TS + quad * 8];
        s16x8 rb1 = *(const s16x8*)&nRT[(nt * 16 + l16) * TS + 32 + quad * 8];
        s16x8 ub0 = *(const s16x8*)&nUT[(nt * 16 + l16) * TS + quad * 8];
        s16x8 ub1 = *(const s16x8*)&nUT[(nt * 16 + l16) * TS + 32 + quad * 8];
        f32x4 z = {};
        f32x4 d0 = MFMA_BF16(va0, kb0, z);
        d0 = MFMA_BF16(va1, kb1, d0);
        d0 = MFMA_BF16(wa0, rb0, d0);
        d0 = MFMA_BF16(wa1, rb1, d0);
        f32x4 pm = MFMA_BF16(wa0, ub0, z);
        pm = MFMA_BF16(wa1, ub1, pm);
        int m0 = mt * 16 + quad * 4, dd = nt * 16 + l16;
        #pragma unroll
        for (int r = 0; r < 4; ++r) {
            D0buf[(size_t)chunk * 1024 + (m0 + r) * 32 + dd] = d0[r];
            Pbuf[(size_t)chunk * 1024 + (m0 + r) * 32 + dd] =
                pm[r] + ((m0 + r) == dd ? 1.f : 0.f);
        }
    }
}

// ---------------------------------------------------------------------------
// scan_states: per (b,h), sequential scan over 64 chunks (fp32).
// BARRIER-FREE: columns of Z are independent under Z_new = P Z_old + D0,
// so each wave owns an 8-column slice with a private Zs[wave][32][8].
// Wave-lockstep + lgkmcnt(0) after publish = correct (verified round 12,
// absmax bit-identical).
// ---------------------------------------------------------------------------
__global__ __launch_bounds__(256) void scan_states(
    const float* __restrict__ Pbuf, const float* __restrict__ D0buf,
    float* __restrict__ Z0buf)
{
    const int bh = blockIdx.x;
    const int tid = threadIdx.x;
    const int wave = tid >> 6, lane = tid & 63;
    const int m = lane >> 1;               // 0..31
    const int jloc = (lane & 1) * 4;       // local col base within wave's 8
    const int j0 = wave * 8 + jloc;        // global col base
    __shared__ __align__(16) float Zs[4][32][8];

    float4 zcur = make_float4(0.f, 0.f, 0.f, 0.f);

    size_t cb = (size_t)bh * 64 * 1024;
    // prefetch chunk 0: full P row m (32 f), D0 quad
    float4 pn[8];
    #pragma unroll
    for (int i = 0; i < 8; ++i)
        pn[i] = *(const float4*)&Pbuf[cb + m * 32 + i * 4];
    float4 dn = *(const float4*)&D0buf[cb + m * 32 + j0];

    for (int c = 0; c < NCHUNK; ++c) {
        float4 pc[8];
        #pragma unroll
        for (int i = 0; i < 8; ++i) pc[i] = pn[i];
        float4 dc = dn;
        size_t cbn = cb + 1024;
        if (c + 1 < NCHUNK) {
            #pragma unroll
            for (int i = 0; i < 8; ++i)
                pn[i] = *(const float4*)&Pbuf[cbn + m * 32 + i * 4];
            dn = *(const float4*)&D0buf[cbn + m * 32 + j0];
        }
        // Z0 (state BEFORE chunk c)
        *(float4*)&Z0buf[cb + m * 32 + j0] = zcur;

        // publish current state; wave-synchronous visibility
        *(float4*)&Zs[wave][m][jloc] = zcur;
        asm volatile("s_waitcnt lgkmcnt(0)" ::: "memory");

        // znew[m][j0..] = sum_mp P[m][mp] * Z[mp][j0..] + D0
        float4 acc = dc;
        #pragma unroll
        for (int i = 0; i < 8; ++i) {
            float pv[4] = {pc[i].x, pc[i].y, pc[i].z, pc[i].w};
            #pragma unroll
            for (int t = 0; t < 4; ++t) {
                float4 zr = *(const float4*)&Zs[wave][i * 4 + t][jloc];
                acc.x = fmaf(pv[t], zr.x, acc.x);
                acc.y = fmaf(pv[t], zr.y, acc.y);
                acc.z = fmaf(pv[t], zr.z, acc.z);
                acc.w = fmaf(pv[t], zr.w, acc.w);
            }
        }
        zcur = acc;
        cb = cbn;
    }
}

// ---------------------------------------------------------------------------
// chunk_out: O = (QZ0^T + tril(QK^T)V - tril(Q(Rt+UZ0)^T)W) * exp(g), bf16 out
// LDS tiles padded (KS/TS/ZS). A1m/nA2m ALIAS the Vb/Wb/Ub/Rb pool (all dead
// before the A1 phase writes): 50,432 B => 3 blocks/CU.
// ---------------------------------------------------------------------------
__global__ __launch_bounds__(256) void chunk_out(
    const unsigned short* __restrict__ qb, const unsigned short* __restrict__ kb,
    const unsigned short* __restrict__ vb, const unsigned short* __restrict__ wb,
    const unsigned short* __restrict__ ub, const unsigned short* __restrict__ rtb,
    const float* __restrict__ Z0buf, const float* __restrict__ gb,
    unsigned short* __restrict__ res_bf)
{
    const int chunk = blockIdx.x;
    const int bh = chunk >> 6, c = chunk & 63;
    const int b = bh >> 3, h = bh & 7;
    const int row0 = b * TT + c * 64;
    const int tid = threadIdx.x;
    const int wave = tid >> 6, lane = tid & 63;
    const int quad = lane >> 4, l16 = lane & 15;

    __shared__ __align__(16) unsigned short Qb[64 * KS], Kb[64 * KS], S2[64 * KS];
    // pool: Vb/Wb/Ub/Rb live until S2 phase; A1m/nA2m written after the
    // barrier that follows -> disjoint lifetimes, alias the same storage.
    __shared__ __align__(16) unsigned short pool[4 * 64 * KS];   // 20,480 B
    unsigned short* Vb = pool;
    unsigned short* Wb = pool + 64 * KS;
    unsigned short* Ub = pool + 2 * 64 * KS;
    unsigned short* Rb = pool + 3 * 64 * KS;
    unsigned short* A1m  = pool;                 // 64*TS shorts
    unsigned short* nA2m = pool + 64 * TS;       // 64*TS shorts (18,432 B total)
    __shared__ __align__(16) unsigned short VT[32 * TS], WT[32 * TS];
    __shared__ __align__(16) unsigned short Z0b[32 * ZS], Z0T[32 * ZS];
    __shared__ float gc[64];

    const size_t cbase = (size_t)chunk * 2048;
    {
        int row = tid >> 2, c8 = (tid & 3) * 8, o = tid * 8;
        *(s16x8*)&Qb[row * KS + c8] = *(const s16x8*)&qb[cbase + o];
        *(s16x8*)&Kb[row * KS + c8] = *(const s16x8*)&kb[cbase + o];
        *(s16x8*)&Vb[row * KS + c8] = *(const s16x8*)&vb[cbase + o];
        *(s16x8*)&Wb[row * KS + c8] = *(const s16x8*)&wb[cbase + o];
        *(s16x8*)&Ub[row * KS + c8] = *(const s16x8*)&ub[cbase + o];
        *(s16x8*)&Rb[row * KS + c8] = *(const s16x8*)&rtb[cbase + o];
    }
    {
        #pragma unroll
        for (int j = 0; j < 4; ++j) {
            int e = tid * 4 + j;
            float z = Z0buf[(size_t)chunk * 1024 + e];
            unsigned short zb = f2bf(z);
            Z0b[(e >> 5) * ZS + (e & 31)] = zb;
            Z0T[(e & 31) * ZS + (e >> 5)] = zb;
        }
    }
    if (tid < 64) gc[tid] = gb[(size_t)chunk * 64 + tid];
    __syncthreads();

    // transposes VT/WT [32][64] (stride TS); m-major lanes
    {
        int m = tid & 31, i0 = (tid >> 5) * 8;
        s16x8 a, b2;
        #pragma unroll
        for (int j = 0; j < 8; ++j) {
            a[j]  = (short)Vb[(i0 + j) * KS + m];
            b2[j] = (short)Wb[(i0 + j) * KS + m];
        }
        *(s16x8*)&VT[m * TS + i0] = a;
        *(s16x8*)&WT[m * TS + i0] = b2;
    }
    // S2 = Rt + U Z0
    {
        s16x8 af = *(const s16x8*)&Ub[(wave * 16 + l16) * KS + quad * 8];
        #pragma unroll
        for (int dt = 0; dt < 2; ++dt) {
            s16x8 bf_ = *(const s16x8*)&Z0T[(dt * 16 + l16) * ZS + quad * 8];
            f32x4 z = {};
            f32x4 acc = MFMA_BF16(af, bf_, z);
            #pragma unroll
            for (int r = 0; r < 4; ++r) {
                int j = wave * 16 + quad * 4 + r;
                int d = dt * 16 + l16;
                float s2 = acc[r] + bf2f(Rb[j * KS + d]);
                S2[j * KS + d] = f2bf(s2);
            }
        }
    }
    __syncthreads();     // Vb/Wb/Ub/Rb dead past this point -> pool reusable

    // A1 = tril(QK^T), nA2 = -tril(Q S2^T)   (inclusive diag)
    {
        s16x8 qf = *(const s16x8*)&Qb[(wave * 16 + l16) * KS + quad * 8];
        #pragma unroll
        for (int jt = 0; jt < 4; ++jt) {
            s16x8 kf = *(const s16x8*)&Kb[(jt * 16 + l16) * KS + quad * 8];
            s16x8 sf = *(const s16x8*)&S2[(jt * 16 + l16) * KS + quad * 8];
            f32x4 z = {};
            f32x4 a1 = MFMA_BF16(qf, kf, z);
            f32x4 a2 = MFMA_BF16(qf, sf, z);
            #pragma unroll
            for (int r = 0; r < 4; ++r) {
                int t = wave * 16 + quad * 4 + r;
                int j = jt * 16 + l16;
                bool keep = (j <= t);
                A1m[t * TS + j]  = keep ? f2bf(a1[r]) : (unsigned short)0;
                nA2m[t * TS + j] = keep ? f2bf(-a2[r]) : (unsigned short)0;
            }
        }
    }
    __syncthreads();

    // O = Q Z0^T + A1m V + nA2m W ; scale exp(g); store bf16
    {
        s16x8 qf = *(const s16x8*)&Qb[(wave * 16 + l16) * KS + quad * 8];
        s16x8 p0 = *(const s16x8*)&A1m[(wave * 16 + l16) * TS + quad * 8];
        s16x8 p1 = *(const s16x8*)&A1m[(wave * 16 + l16) * TS + 32 + quad * 8];
        s16x8 m0 = *(const s16x8*)&nA2m[(wave * 16 + l16) * TS + quad * 8];
        s16x8 m1 = *(const s16x8*)&nA2m[(wave * 16 + l16) * TS + 32 + quad * 8];
        #pragma unroll
        for (int mt = 0; mt < 2; ++mt) {
            s16x8 zf = *(const s16x8*)&Z0b[(mt * 16 + l16) * ZS + quad * 8];
            s16x8 v0 = *(const s16x8*)&VT[(mt * 16 + l16) * TS + quad * 8];
            s16x8 v1 = *(const s16x8*)&VT[(mt * 16 + l16) * TS + 32 + quad * 8];
            s16x8 w0 = *(const s16x8*)&WT[(mt * 16 + l16) * TS + quad * 8];
            s16x8 w1 = *(const s16x8*)&WT[(mt * 16 + l16) * TS + 32 + quad * 8];
            f32x4 z = {};
            f32x4 acc = MFMA_BF16(qf, zf, z);
            acc = MFMA_BF16(p0, v0, acc);
            acc = MFMA_BF16(p1, v1, acc);
            acc = MFMA_BF16(m0, w0, acc);
            acc = MFMA_BF16(m1, w1, acc);
            #pragma unroll
            for (int r = 0; r < 4; ++r) {
                int t = wave * 16 + quad * 4 + r;
                int m = mt * 16 + l16;
                float e = expf(gc[t]);
                res_bf[(size_t)(row0 + t) * 256 + h * 32 + m] = f2bf(acc[r] * e);
            }
        }
    }
}

// ---------------------------------------------------------------------------
extern "C" void kernel_launch(void* const* d_in, const int* in_sizes, int n_in,
                              void* d_out, int out_size, void* d_ws, size_t ws_size,
                              hipStream_t stream)
{
    const float* x     = (const float*)d_in[0];
    const float* Wq    = (const float*)d_in[1];
    const float* Wk    = (const float*)d_in[2];
    const float* Wv    = (const float*)d_in[3];
    const float* Ww    = (const float*)d_in[4];
    const float* Wbeta = (const float*)d_in[5];
    const float* bbeta = (const float*)d_in[6];
    const float* Wg    = (const float*)d_in[7];
    const float* bg    = (const float*)d_in[8];
    const float* Wo    = (const float*)d_in[9];
    float* out = (float*)d_out;

    unsigned short* x_bf       = (unsigned short*)d_ws;           // 8,388,608
    unsigned short* stacked_bf = x_bf + (size_t)NROW * HID;       // 589,824
    unsigned short* Wo_bf      = stacked_bf + (size_t)NPAD * HID; // 131,072
    unsigned short* qb  = Wo_bf + (size_t)HID * 256;              // 4,194,304 each
    unsigned short* kb  = qb + (size_t)NROW * 256;
    unsigned short* vb  = kb + (size_t)NROW * 256;
    unsigned short* wbv = vb + (size_t)NROW * 256;
    unsigned short* ub  = wbv + (size_t)NROW * 256;
    unsigned short* rtb = ub + (size_t)NROW * 256;
    unsigned short* res_bf = rtb + (size_t)NROW * 256;
    float* betab = (float*)(res_bf + (size_t)NROW * 256);         // 131,072 f
    float* gb    = betab + (size_t)NROW * 8;
    float* D0buf = gb + (size_t)NROW * 8;                         // 2,097,152 f each
    float* Pbuf  = D0buf + (size_t)2048 * 1024;
    float* Z0buf = Pbuf + (size_t)2048 * 1024;

    // 1. casts + weight concat
    cast_bf16<<<(NROW * HID / 4 + 255) / 256, 256, 0, stream>>>(x, x_bf, NROW * HID / 4);
    cast_bf16<<<(HID * 256 / 4 + 255) / 256, 256, 0, stream>>>(Wo, Wo_bf, HID * 256 / 4);
    concat_w_bf<<<(NPAD * HID + 255) / 256, 256, 0, stream>>>(Wq, Wk, Wv, Ww, Wbeta, Wg, stacked_bf);

    // 2. projection GEMM -> head-major bf16 q/k/v/w + fp32 beta/g
    //    (1-D grid, XCD-aware bijective remap inside the kernel)
    gemm_proj<<<NROW / 128 * (NPAD / 128), 256, 0, stream>>>(
        x_bf, stacked_bf, qb, kb, vb, wbv, betab, gb, bbeta, bg);

    // 3. chunked delta-rule precompute (MFMA, pooled LDS -> 3 blocks/CU)
    chunk_pre<<<2048, 256, 0, stream>>>(kb, vb, wbv, betab, ub, rtb, D0buf, Pbuf);

    // 4. chunk-state scan (barrier-free per-wave column slices)
    scan_states<<<32, 256, 0, stream>>>(Pbuf, D0buf, Z0buf);

    // 5. Z-dependent output terms (MFMA, writes bf16 res)
    chunk_out<<<2048, 256, 0, stream>>>(qb, kb, vb, wbv, ub, rtb, Z0buf, gb, res_bf);

    // 6. output GEMM: out = res @ Wo^T (2-D grid, remap reverted)
    gemm_out<<<dim3(NROW / 128, HID / 128), 256, 0, stream>>>(res_bf, Wo_bf, out);
}

// Round 16
// 247.393 us; speedup vs baseline: 1.0375x; 1.0071x over previous
//
#include <hip/hip_runtime.h>
#include <hip/hip_bf16.h>
#include <math.h>

// Problem constants
#define BATCH 4
#define TT 4096
#define HID 512
#define NH 8
#define HD 32
#define NROW (BATCH * TT)       // 16384
#define NPAD 1152               // padded col count for 128-wide MFMA tiles
#define QSCALE 0.17677669529663687f  // 32^-0.5
#define NCHUNK 64               // chunks per (b,h); chunk length 64

// padded LDS strides (shorts): odd multiples of 8 -> conflict-free b128 rows
#define KS 40                   // for [64][32] bf16 tiles (80B rows)
#define TS 72                   // for [32][64]/[64][64] bf16 tiles (144B rows)
#define ZS 40                   // for [32][32] bf16 tiles
#define XS 36                   // f32 [64][36] X tiles (144B rows, 16B aligned)

using s16x8 = __attribute__((ext_vector_type(8))) short;
using f32x4 = __attribute__((ext_vector_type(4))) float;

#define MFMA_BF16(a, b, c) __builtin_amdgcn_mfma_f32_16x16x32_bf16((a), (b), (c), 0, 0, 0)

__device__ __forceinline__ unsigned short f2bf(float v) {
    __hip_bfloat16 h = __float2bfloat16(v);
    unsigned short u;
    __builtin_memcpy(&u, &h, 2);
    return u;
}
__device__ __forceinline__ float bf2f(unsigned short u) {
    unsigned int x = ((unsigned int)u) << 16;
    float f;
    __builtin_memcpy(&f, &x, 4);
    return f;
}
// async global->LDS, 16B per lane; LDS dest = wave-uniform base + lane*16
__device__ __forceinline__ void gload_lds16(const unsigned short* g, unsigned short* l) {
    __builtin_amdgcn_global_load_lds(
        (const __attribute__((address_space(1))) void*)g,
        (__attribute__((address_space(3))) void*)l, 16, 0, 0);
}

// ---------------------------------------------------------------------------
// cast fp32 -> bf16, 4 elements per thread
// ---------------------------------------------------------------------------
__global__ __launch_bounds__(256) void cast_bf16(
    const float* __restrict__ src, unsigned short* __restrict__ dst, int n4)
{
    int i = blockIdx.x * 256 + threadIdx.x;
    if (i >= n4) return;
    float4 v = ((const float4*)src)[i];
    ushort4 o;
    o.x = f2bf(v.x); o.y = f2bf(v.y); o.z = f2bf(v.z); o.w = f2bf(v.w);
    ((ushort4*)dst)[i] = o;
}

// ---------------------------------------------------------------------------
// concat weights into stacked bf16 [1152][512]; fold q-scale; zero pad rows
// ---------------------------------------------------------------------------
__global__ __launch_bounds__(256) void concat_w_bf(
    const float* __restrict__ Wq, const float* __restrict__ Wk,
    const float* __restrict__ Wv, const float* __restrict__ Ww,
    const float* __restrict__ Wbeta, const float* __restrict__ Wg,
    unsigned short* __restrict__ dst)
{
    int o = blockIdx.x * 256 + threadIdx.x;   // < 1152*512
    if (o >= NPAD * HID) return;
    int r = o >> 9;                           // /512
    float v;
    if      (r < 256)  v = Wq[o] * QSCALE;
    else if (r < 512)  v = Wk[o - 256 * 512];
    else if (r < 768)  v = Wv[o - 512 * 512];
    else if (r < 1024) v = Ww[o - 768 * 512];
    else if (r < 1032) v = Wbeta[o - 1024 * 512];
    else if (r < 1040) v = Wg[o - 1032 * 512];
    else               v = 0.0f;
    dst[o] = f2bf(v);
}

// ---------------------------------------------------------------------------
// Projection GEMM (bf16 MFMA): [16384,512] x [1152,512]^T.
// 3-buffer global_load_lds pipeline, counted vmcnt(4) + raw s_barrier.
// (2-buffer variants RACE: counted-vmcnt overlap needs prefetch distance
//  >= 2 barrier intervals => >= 3 buffers. Rounds 14/15 proved both
//  2-buffer orderings wrong.)
// LDS XOR-swizzle (conflict-free, round 6). XCD-aware bijective remap
// (round 9). NO s_setprio (round 7: starves prefetch issue).
// ---------------------------------------------------------------------------
__global__ __launch_bounds__(256) void gemm_proj(
    const unsigned short* __restrict__ A, const unsigned short* __restrict__ B,
    unsigned short* __restrict__ qb, unsigned short* __restrict__ kb,
    unsigned short* __restrict__ vb, unsigned short* __restrict__ wbv,
    float* __restrict__ betab, float* __restrict__ gb,
    const float* __restrict__ bbeta, const float* __restrict__ bg)
{
    __shared__ __align__(16) unsigned short smem[3 * 8192];   // 49,152 B
    unsigned short* Cs = smem;            // epilogue tile [128][132], aliases staging

    const int tid = threadIdx.x;
    const int wave = tid >> 6, lane = tid & 63;
    const int quad = lane >> 4, l16 = lane & 15;
    const int wr = wave & 1, wc = wave >> 1;
    // XCD-aware remap: wid -> (xcd, idx) -> (row-block, col-block)
    const int wid = blockIdx.x;               // 0..1151
    const int xcd = wid & 7, idx = wid >> 3;  // idx 0..143
    const int rb = xcd * 16 + idx / 9;        // 0..127
    const int cb = idx % 9;                   // 0..8
    const int r0 = rb * 128;
    const int c0 = cb * 128;
    const int K = HID;
    const int NSTEP = 16;                 // K/32
    const int swz = (l16 >> 1) & 3;       // read-side XOR (row bits 1-2)

    f32x4 acc[4][4] = {};

    auto stage = [&](int k0, int b) {
        unsigned short* Ab = smem + b * 8192;
        unsigned short* Bb = Ab + 4096;
        #pragma unroll
        for (int i = 0; i < 2; ++i) {
            int slot = wave * 128 + i * 64 + lane;
            int row = slot >> 2;
            int kq = (slot & 3) ^ ((row >> 1) & 3);
            gload_lds16(&A[(size_t)(r0 + row) * K + k0 + kq * 8], &Ab[(wave * 128 + i * 64) * 8]);
            gload_lds16(&B[(size_t)(c0 + row) * K + k0 + kq * 8], &Bb[(wave * 128 + i * 64) * 8]);
        }
    };

    stage(0, 0);
    stage(32, 1);
    int cur = 0, pf = 2;
    for (int it = 0; it < NSTEP; ++it) {
        if (it < NSTEP - 1) asm volatile("s_waitcnt vmcnt(4) lgkmcnt(0)" ::: "memory");
        else                asm volatile("s_waitcnt vmcnt(0) lgkmcnt(0)" ::: "memory");
        __builtin_amdgcn_s_barrier();
        if (it + 2 < NSTEP) stage((it + 2) * 32, pf);
        const unsigned short* As = smem + cur * 8192;
        const unsigned short* Bs = As + 4096;
        s16x8 af[4], bf[4];
        #pragma unroll
        for (int mi = 0; mi < 4; ++mi)
            af[mi] = *(const s16x8*)&As[(wr * 64 + mi * 16 + l16) * 32 + (quad ^ swz) * 8];
        #pragma unroll
        for (int ni = 0; ni < 4; ++ni)
            bf[ni] = *(const s16x8*)&Bs[(wc * 64 + ni * 16 + l16) * 32 + (quad ^ swz) * 8];
        #pragma unroll
        for (int mi = 0; mi < 4; ++mi)
            #pragma unroll
            for (int ni = 0; ni < 4; ++ni)
                acc[mi][ni] = MFMA_BF16(af[mi], bf[ni], acc[mi][ni]);
        pf = cur;
        cur = (cur + 1 == 3) ? 0 : cur + 1;
    }

    if (cb < 8) {
        // ---- q/k/v/w: LDS transpose + coalesced 16B stores ----
        __syncthreads();
        #pragma unroll
        for (int mi = 0; mi < 4; ++mi)
            #pragma unroll
            for (int ni = 0; ni < 4; ++ni) {
                int col = wc * 64 + ni * 16 + l16;
                #pragma unroll
                for (int r = 0; r < 4; ++r) {
                    int row = wr * 64 + mi * 16 + quad * 4 + r;
                    Cs[row * 132 + col] = f2bf(acc[mi][ni][r]);
                }
            }
        __syncthreads();
        const int sub = cb >> 1;
        unsigned short* dst = (sub == 0) ? qb : (sub == 1) ? kb : (sub == 2) ? vb : wbv;
        const int hh0 = (cb & 1) * 4;
        const int bb = r0 >> 12, t0 = r0 & 4095;
        #pragma unroll
        for (int u = 0; u < 2; ++u) {
            int unit = tid + u * 256;          // 0..511
            int grp = unit >> 7, row = unit & 127;
            size_t gbase = ((size_t)(bb * 8 + hh0 + grp) * 4096 + t0 + row) * 32;
            #pragma unroll
            for (int i = 0; i < 4; ++i) {
                s16x8 v = *(const s16x8*)&Cs[row * 132 + grp * 32 + i * 8];
                *(s16x8*)&dst[gbase + i * 8] = v;
            }
        }
    } else {
        // ---- beta/g columns: scalar epilogue with transcendentals ----
        #pragma unroll
        for (int mi = 0; mi < 4; ++mi) {
            #pragma unroll
            for (int ni = 0; ni < 4; ++ni) {
                int col = c0 + wc * 64 + ni * 16 + l16;
                if (col >= 1040) continue;
                #pragma unroll
                for (int r = 0; r < 4; ++r) {
                    int row = r0 + wr * 64 + mi * 16 + quad * 4 + r;
                    int bb = row >> 12, t = row & 4095;
                    float v = acc[mi][ni][r];
                    if (col < 1032) {
                        float z = v + bbeta[col - 1024];
                        betab[(size_t)(bb * 8 + col - 1024) * 4096 + t] = 2.0f / (1.0f + expf(-z));
                    } else {
                        float z = v + bg[col - 1032];
                        gb[(size_t)(bb * 8 + col - 1032) * 4096 + t] =
                            fminf(z, 0.0f) - log1pf(expf(-fabsf(z)));
                    }
                }
            }
        }
    }
}

// ---------------------------------------------------------------------------
// Output GEMM (bf16 MFMA): out[16384,512] = res_bf[16384,256] @ Wo_bf[512,256]^T
// 3-buffer counted-vmcnt pipeline + LDS XOR-swizzle. 2-D grid. K=256 -> 8 steps.
// ---------------------------------------------------------------------------
__global__ __launch_bounds__(256) void gemm_out(
    const unsigned short* __restrict__ A, const unsigned short* __restrict__ B,
    float* __restrict__ C)
{
    __shared__ __align__(16) unsigned short smem[3 * 8192];
    const int tid = threadIdx.x;
    const int wave = tid >> 6, lane = tid & 63;
    const int quad = lane >> 4, l16 = lane & 15;
    const int wr = wave & 1, wc = wave >> 1;
    const int r0 = blockIdx.x * 128;
    const int c0 = blockIdx.y * 128;
    const int K = 256;
    const int NSTEP = 8;
    const int swz = (l16 >> 1) & 3;

    f32x4 acc[4][4] = {};

    auto stage = [&](int k0, int b) {
        unsigned short* Ab = smem + b * 8192;
        unsigned short* Bb = Ab + 4096;
        #pragma unroll
        for (int i = 0; i < 2; ++i) {
            int slot = wave * 128 + i * 64 + lane;
            int row = slot >> 2;
            int kq = (slot & 3) ^ ((row >> 1) & 3);
            gload_lds16(&A[(size_t)(r0 + row) * K + k0 + kq * 8], &Ab[(wave * 128 + i * 64) * 8]);
            gload_lds16(&B[(size_t)(c0 + row) * K + k0 + kq * 8], &Bb[(wave * 128 + i * 64) * 8]);
        }
    };

    stage(0, 0);
    stage(32, 1);
    int cur = 0, pf = 2;
    for (int it = 0; it < NSTEP; ++it) {
        if (it < NSTEP - 1) asm volatile("s_waitcnt vmcnt(4) lgkmcnt(0)" ::: "memory");
        else                asm volatile("s_waitcnt vmcnt(0) lgkmcnt(0)" ::: "memory");
        __builtin_amdgcn_s_barrier();
        if (it + 2 < NSTEP) stage((it + 2) * 32, pf);
        const unsigned short* As = smem + cur * 8192;
        const unsigned short* Bs = As + 4096;
        s16x8 af[4], bf[4];
        #pragma unroll
        for (int mi = 0; mi < 4; ++mi)
            af[mi] = *(const s16x8*)&As[(wr * 64 + mi * 16 + l16) * 32 + (quad ^ swz) * 8];
        #pragma unroll
        for (int ni = 0; ni < 4; ++ni)
            bf[ni] = *(const s16x8*)&Bs[(wc * 64 + ni * 16 + l16) * 32 + (quad ^ swz) * 8];
        #pragma unroll
        for (int mi = 0; mi < 4; ++mi)
            #pragma unroll
            for (int ni = 0; ni < 4; ++ni)
                acc[mi][ni] = MFMA_BF16(af[mi], bf[ni], acc[mi][ni]);
        pf = cur;
        cur = (cur + 1 == 3) ? 0 : cur + 1;
    }

    #pragma unroll
    for (int mi = 0; mi < 4; ++mi)
        #pragma unroll
        for (int ni = 0; ni < 4; ++ni) {
            int col = c0 + wc * 64 + ni * 16 + l16;
            #pragma unroll
            for (int r = 0; r < 4; ++r) {
                int row = r0 + wr * 64 + mi * 16 + quad * 4 + r;
                C[(size_t)row * HID + col] = acc[mi][ni][r];
            }
        }
}

// ---------------------------------------------------------------------------
// chunk_pre: per-chunk WY precompute via MFMA. One block (256 thr) per chunk.
// Hand-pooled LDS with lifetime aliasing + packed-triangular G (round 11).
// ---------------------------------------------------------------------------
__global__ __launch_bounds__(256) void chunk_pre(
    const unsigned short* __restrict__ kb, const unsigned short* __restrict__ vb,
    unsigned short* __restrict__ wb, const float* __restrict__ betab,
    unsigned short* __restrict__ ub, unsigned short* __restrict__ rtb,
    float* __restrict__ D0buf, float* __restrict__ Pbuf)
{
    const int chunk = blockIdx.x;
    const int tid = threadIdx.x;
    const int wave = tid >> 6, lane = tid & 63;
    const int quad = lane >> 4, l16 = lane & 15;

    __shared__ __align__(16) unsigned short pool[19200];
    __shared__ __align__(16) float Gp[2016];
    __shared__ float betac[64];

    unsigned short* Kb  = pool;
    unsigned short* Vb  = pool + 2560;
    unsigned short* Wb  = pool + 5120;
    unsigned short* KT  = pool + 7680;
    unsigned short* VT  = pool + 9984;
    unsigned short* WT  = pool + 12288;
    unsigned short* Pbf = pool + 14592;
    float* XA = (float*)pool;                 // [64][XS], aliases Kb+Vb
    float* XB = (float*)(pool + 14592);       // [64][XS], aliases Pbf
    unsigned short* nUT = pool;               // [32][TS], aliases XA region
    unsigned short* nRT = pool + 2304;        // [32][TS]

    const size_t cbase = (size_t)chunk * 2048;

    {
        int row = tid >> 2, c8 = (tid & 3) * 8, o = tid * 8;
        *(s16x8*)&Kb[row * KS + c8] = *(const s16x8*)&kb[cbase + o];
        *(s16x8*)&Vb[row * KS + c8] = *(const s16x8*)&vb[cbase + o];
        // w: normalize inline. Each 4-lane group (same row) reduces ||w||^2.
        s16x8 wv = *(const s16x8*)&wb[cbase + o];
        float ss = 0.f;
        #pragma unroll
        for (int j = 0; j < 8; ++j) { float w = bf2f((unsigned short)wv[j]); ss = fmaf(w, w, ss); }
        ss += __shfl_xor(ss, 1);
        ss += __shfl_xor(ss, 2);
        float s = 1.f / (sqrtf(ss) + 1e-6f);
        s16x8 ov;
        #pragma unroll
        for (int j = 0; j < 8; ++j) ov[j] = (short)f2bf(bf2f((unsigned short)wv[j]) * s);
        *(s16x8*)&Wb[row * KS + c8] = ov;
        *(s16x8*)&wb[cbase + o] = ov;      // normalized w for chunk_out
    }
    if (tid < 64) betac[tid] = betab[(size_t)chunk * 64 + tid];
    __syncthreads();

    // transposed bf16 tiles KT/VT/WT [32][64] (stride TS); m-major lanes
    {
        int m = tid & 31, i0 = (tid >> 5) * 8;
        s16x8 a, b2, c2;
        #pragma unroll
        for (int j = 0; j < 8; ++j) {
            a[j]  = (short)Kb[(i0 + j) * KS + m];
            b2[j] = (short)Vb[(i0 + j) * KS + m];
            c2[j] = (short)Wb[(i0 + j) * KS + m];
        }
        *(s16x8*)&KT[m * TS + i0] = a;
        *(s16x8*)&VT[m * TS + i0] = b2;
        *(s16x8*)&WT[m * TS + i0] = c2;
    }
    // Gp = packed strict-tril(beta*W W^T) (f32); Pbf = strict-tril(beta*W V^T) (bf16)
    {
        s16x8 af = *(const s16x8*)&Wb[(wave * 16 + l16) * KS + quad * 8];
        #pragma unroll
        for (int jt = 0; jt < 4; ++jt) {
            s16x8 bw = *(const s16x8*)&Wb[(jt * 16 + l16) * KS + quad * 8];
            s16x8 bv = *(const s16x8*)&Vb[(jt * 16 + l16) * KS + quad * 8];
            f32x4 z = {};
            f32x4 aG = MFMA_BF16(af, bw, z);
            f32x4 aP = MFMA_BF16(af, bv, z);
            #pragma unroll
            for (int r = 0; r < 4; ++r) {
                int t = wave * 16 + quad * 4 + r;
                int j = jt * 16 + l16;
                float bt = betac[t];
                if (j < t) {
                    Gp[t * (t - 1) / 2 + j] = bt * aG[r];
                    Pbf[t * TS + j] = f2bf(bt * aP[r]);
                } else {
                    Pbf[t * TS + j] = 0;
                }
            }
        }
    }
    __syncthreads();

    // RHS: XA = beta*W ; XB = Pbf @ K (via KT). XB aliases Pbf: load frags
    // to regs, barrier, then MFMA+write.
    {
        s16x8 a0 = *(const s16x8*)&Pbf[(wave * 16 + l16) * TS + quad * 8];
        s16x8 a1 = *(const s16x8*)&Pbf[(wave * 16 + l16) * TS + 32 + quad * 8];
        s16x8 b0[2], b1[2];
        #pragma unroll
        for (int dt = 0; dt < 2; ++dt) {
            b0[dt] = *(const s16x8*)&KT[(dt * 16 + l16) * TS + quad * 8];
            b1[dt] = *(const s16x8*)&KT[(dt * 16 + l16) * TS + 32 + quad * 8];
        }
        // XA = beta*W (writes Kb+Vb region -- dead; reads Wb -- not aliased)
        {
            int r = tid >> 2, cc0 = (tid & 3) * 8;
            float bt = betac[r];
            s16x8 wv = *(const s16x8*)&Wb[r * KS + cc0];
            #pragma unroll
            for (int j = 0; j < 8; ++j) XA[r * XS + cc0 + j] = bt * bf2f((unsigned short)wv[j]);
        }
        __syncthreads();           // all Pbf reads complete before XB writes
        #pragma unroll
        for (int dt = 0; dt < 2; ++dt) {
            f32x4 z = {};
            f32x4 acc = MFMA_BF16(a0, b0[dt], z);
            acc = MFMA_BF16(a1, b1[dt], acc);
            #pragma unroll
            for (int r = 0; r < 4; ++r)
                XB[(wave * 16 + quad * 4 + r) * XS + dt * 16 + l16] = acc[r];
        }
    }

    // blocked forward substitution on XA(cols 0-31) / XB(cols 32-63)
    for (int tb = 0; tb < 64; tb += 16) {
        __syncthreads();
        if (tid < 64) {
            float* Xp = (tid < 32) ? XA : XB;
            int c = tid & 31;
            float xv[16];
            #pragma unroll
            for (int i = 0; i < 16; ++i) xv[i] = Xp[(tb + i) * XS + c];
            #pragma unroll
            for (int j = 1; j < 16; ++j) {
                int gbase = (tb + j) * (tb + j - 1) / 2 + tb;
                #pragma unroll
                for (int i = 0; i < j; ++i)
                    xv[j] = fmaf(-Gp[gbase + i], xv[i], xv[j]);
            }
            #pragma unroll
            for (int i = 1; i < 16; ++i) Xp[(tb + i) * XS + c] = xv[i];
        }
        __syncthreads();
        if (tb < 48) {
            int n4 = (48 - tb) * 16;
            for (int idx = tid; idx < n4; idx += 256) {
                int t = tb + 16 + (idx >> 4);
                int colq = idx & 15;
                float* Xp = (colq < 8) ? XA : XB;
                int cc = (colq & 7) * 4;
                int gbase = t * (t - 1) / 2 + tb;
                float4 acc = *(float4*)&Xp[t * XS + cc];
                #pragma unroll
                for (int i = 0; i < 16; ++i) {
                    float g = Gp[gbase + i];
                    float4 xs = *(const float4*)&Xp[(tb + i) * XS + cc];
                    acc.x = fmaf(-g, xs.x, acc.x);
                    acc.y = fmaf(-g, xs.y, acc.y);
                    acc.z = fmaf(-g, xs.z, acc.z);
                    acc.w = fmaf(-g, xs.w, acc.w);
                }
                *(float4*)&Xp[t * XS + cc] = acc;
            }
        }
    }
    __syncthreads();

    // write U,Rt bf16 global; reg-stage negated transposes; barrier; write
    // nUT/nRT into the XA region (all XA/XB reads complete first).
    {
        int r = tid >> 2, c8 = (tid & 3) * 8;
        s16x8 uv, rv;
        #pragma unroll
        for (int j = 0; j < 8; ++j) {
            uv[j] = (short)f2bf(XA[r * XS + c8 + j]);
            rv[j] = (short)f2bf(XB[r * XS + c8 + j]);
        }
        *(s16x8*)&ub[cbase + r * 32 + c8] = uv;
        *(s16x8*)&rtb[cbase + r * 32 + c8] = rv;
    }
    {
        int d = tid & 31, i0 = (tid >> 5) * 8;
        s16x8 u2, r2;
        #pragma unroll
        for (int j = 0; j < 8; ++j) {
            u2[j] = (short)f2bf(-XA[(i0 + j) * XS + d]);
            r2[j] = (short)f2bf(-XB[(i0 + j) * XS + d]);
        }
        __syncthreads();           // all XA/XB reads done before overwrite
        *(s16x8*)&nUT[d * TS + i0] = u2;
        *(s16x8*)&nRT[d * TS + i0] = r2;
    }
    __syncthreads();

    // D0 = V^T K - W^T Rt ; Pmat = I - W^T U   (one 16x16 tile per wave)
    {
        int mt = wave >> 1, nt = wave & 1;
        s16x8 va0 = *(const s16x8*)&VT[(mt * 16 + l16) * TS + quad * 8];
        s16x8 va1 = *(const s16x8*)&VT[(mt * 16 + l16) * TS + 32 + quad * 8];
        s16x8 wa0 = *(const s16x8*)&WT[(mt * 16 + l16) * TS + quad * 8];
        s16x8 wa1 = *(const s16x8*)&WT[(mt * 16 + l16) * TS + 32 + quad * 8];
        s16x8 kb0 = *(const s16x8*)&KT[(nt * 16 + l16) * TS + quad * 8];
        s16x8 kb1 = *(const s16x8*)&KT[(nt * 16 + l16) * TS + 32 + quad * 8];
        s16x8 rb0 = *(const s16x8*)&nRT[(nt * 16 + l16) * TS + quad * 8];
        s16x8 rb1 = *(const s16x8*)&nRT[(nt * 16 + l16) * TS + 32 + quad * 8];
        s16x8 ub0 = *(const s16x8*)&nUT[(nt * 16 + l16) * TS + quad * 8];
        s16x8 ub1 = *(const s16x8*)&nUT[(nt * 16 + l16) * TS + 32 + quad * 8];
        f32x4 z = {};
        f32x4 d0 = MFMA_BF16(va0, kb0, z);
        d0 = MFMA_BF16(va1, kb1, d0);
        d0 = MFMA_BF16(wa0, rb0, d0);
        d0 = MFMA_BF16(wa1, rb1, d0);
        f32x4 pm = MFMA_BF16(wa0, ub0, z);
        pm = MFMA_BF16(wa1, ub1, pm);
        int m0 = mt * 16 + quad * 4, dd = nt * 16 + l16;
        #pragma unroll
        for (int r = 0; r < 4; ++r) {
            D0buf[(size_t)chunk * 1024 + (m0 + r) * 32 + dd] = d0[r];
            Pbuf[(size_t)chunk * 1024 + (m0 + r) * 32 + dd] =
                pm[r] + ((m0 + r) == dd ? 1.f : 0.f);
        }
    }
}

// ---------------------------------------------------------------------------
// scan_states: per (b,h), sequential scan over 64 chunks (fp32).
// BARRIER-FREE: columns of Z are independent under Z_new = P Z_old + D0,
// so each wave owns an 8-column slice with a private Zs[wave][32][8].
// Wave-lockstep + lgkmcnt(0) after publish = correct (verified round 12,
// absmax bit-identical).
// ---------------------------------------------------------------------------
__global__ __launch_bounds__(256) void scan_states(
    const float* __restrict__ Pbuf, const float* __restrict__ D0buf,
    float* __restrict__ Z0buf)
{
    const int bh = blockIdx.x;
    const int tid = threadIdx.x;
    const int wave = tid >> 6, lane = tid & 63;
    const int m = lane >> 1;               // 0..31
    const int jloc = (lane & 1) * 4;       // local col base within wave's 8
    const int j0 = wave * 8 + jloc;        // global col base
    __shared__ __align__(16) float Zs[4][32][8];

    float4 zcur = make_float4(0.f, 0.f, 0.f, 0.f);

    size_t cb = (size_t)bh * 64 * 1024;
    // prefetch chunk 0: full P row m (32 f), D0 quad
    float4 pn[8];
    #pragma unroll
    for (int i = 0; i < 8; ++i)
        pn[i] = *(const float4*)&Pbuf[cb + m * 32 + i * 4];
    float4 dn = *(const float4*)&D0buf[cb + m * 32 + j0];

    for (int c = 0; c < NCHUNK; ++c) {
        float4 pc[8];
        #pragma unroll
        for (int i = 0; i < 8; ++i) pc[i] = pn[i];
        float4 dc = dn;
        size_t cbn = cb + 1024;
        if (c + 1 < NCHUNK) {
            #pragma unroll
            for (int i = 0; i < 8; ++i)
                pn[i] = *(const float4*)&Pbuf[cbn + m * 32 + i * 4];
            dn = *(const float4*)&D0buf[cbn + m * 32 + j0];
        }
        // Z0 (state BEFORE chunk c)
        *(float4*)&Z0buf[cb + m * 32 + j0] = zcur;

        // publish current state; wave-synchronous visibility
        *(float4*)&Zs[wave][m][jloc] = zcur;
        asm volatile("s_waitcnt lgkmcnt(0)" ::: "memory");

        // znew[m][j0..] = sum_mp P[m][mp] * Z[mp][j0..] + D0
        float4 acc = dc;
        #pragma unroll
        for (int i = 0; i < 8; ++i) {
            float pv[4] = {pc[i].x, pc[i].y, pc[i].z, pc[i].w};
            #pragma unroll
            for (int t = 0; t < 4; ++t) {
                float4 zr = *(const float4*)&Zs[wave][i * 4 + t][jloc];
                acc.x = fmaf(pv[t], zr.x, acc.x);
                acc.y = fmaf(pv[t], zr.y, acc.y);
                acc.z = fmaf(pv[t], zr.z, acc.z);
                acc.w = fmaf(pv[t], zr.w, acc.w);
            }
        }
        zcur = acc;
        cb = cbn;
    }
}

// ---------------------------------------------------------------------------
// chunk_out: O = (QZ0^T + tril(QK^T)V - tril(Q(Rt+UZ0)^T)W) * exp(g), bf16 out
// LDS tiles padded (KS/TS/ZS). A1m/nA2m ALIAS the Vb/Wb/Ub/Rb pool (all dead
// before the A1 phase writes): 50,432 B => 3 blocks/CU.
// ---------------------------------------------------------------------------
__global__ __launch_bounds__(256) void chunk_out(
    const unsigned short* __restrict__ qb, const unsigned short* __restrict__ kb,
    const unsigned short* __restrict__ vb, const unsigned short* __restrict__ wb,
    const unsigned short* __restrict__ ub, const unsigned short* __restrict__ rtb,
    const float* __restrict__ Z0buf, const float* __restrict__ gb,
    unsigned short* __restrict__ res_bf)
{
    const int chunk = blockIdx.x;
    const int bh = chunk >> 6, c = chunk & 63;
    const int b = bh >> 3, h = bh & 7;
    const int row0 = b * TT + c * 64;
    const int tid = threadIdx.x;
    const int wave = tid >> 6, lane = tid & 63;
    const int quad = lane >> 4, l16 = lane & 15;

    __shared__ __align__(16) unsigned short Qb[64 * KS], Kb[64 * KS], S2[64 * KS];
    // pool: Vb/Wb/Ub/Rb live until S2 phase; A1m/nA2m written after the
    // barrier that follows -> disjoint lifetimes, alias the same storage.
    __shared__ __align__(16) unsigned short pool[4 * 64 * KS];   // 20,480 B
    unsigned short* Vb = pool;
    unsigned short* Wb = pool + 64 * KS;
    unsigned short* Ub = pool + 2 * 64 * KS;
    unsigned short* Rb = pool + 3 * 64 * KS;
    unsigned short* A1m  = pool;                 // 64*TS shorts
    unsigned short* nA2m = pool + 64 * TS;       // 64*TS shorts (18,432 B total)
    __shared__ __align__(16) unsigned short VT[32 * TS], WT[32 * TS];
    __shared__ __align__(16) unsigned short Z0b[32 * ZS], Z0T[32 * ZS];
    __shared__ float gc[64];

    const size_t cbase = (size_t)chunk * 2048;
    {
        int row = tid >> 2, c8 = (tid & 3) * 8, o = tid * 8;
        *(s16x8*)&Qb[row * KS + c8] = *(const s16x8*)&qb[cbase + o];
        *(s16x8*)&Kb[row * KS + c8] = *(const s16x8*)&kb[cbase + o];
        *(s16x8*)&Vb[row * KS + c8] = *(const s16x8*)&vb[cbase + o];
        *(s16x8*)&Wb[row * KS + c8] = *(const s16x8*)&wb[cbase + o];
        *(s16x8*)&Ub[row * KS + c8] = *(const s16x8*)&ub[cbase + o];
        *(s16x8*)&Rb[row * KS + c8] = *(const s16x8*)&rtb[cbase + o];
    }
    {
        #pragma unroll
        for (int j = 0; j < 4; ++j) {
            int e = tid * 4 + j;
            float z = Z0buf[(size_t)chunk * 1024 + e];
            unsigned short zb = f2bf(z);
            Z0b[(e >> 5) * ZS + (e & 31)] = zb;
            Z0T[(e & 31) * ZS + (e >> 5)] = zb;
        }
    }
    if (tid < 64) gc[tid] = gb[(size_t)chunk * 64 + tid];
    __syncthreads();

    // transposes VT/WT [32][64] (stride TS); m-major lanes
    {
        int m = tid & 31, i0 = (tid >> 5) * 8;
        s16x8 a, b2;
        #pragma unroll
        for (int j = 0; j < 8; ++j) {
            a[j]  = (short)Vb[(i0 + j) * KS + m];
            b2[j] = (short)Wb[(i0 + j) * KS + m];
        }
        *(s16x8*)&VT[m * TS + i0] = a;
        *(s16x8*)&WT[m * TS + i0] = b2;
    }
    // S2 = Rt + U Z0
    {
        s16x8 af = *(const s16x8*)&Ub[(wave * 16 + l16) * KS + quad * 8];
        #pragma unroll
        for (int dt = 0; dt < 2; ++dt) {
            s16x8 bf_ = *(const s16x8*)&Z0T[(dt * 16 + l16) * ZS + quad * 8];
            f32x4 z = {};
            f32x4 acc = MFMA_BF16(af, bf_, z);
            #pragma unroll
            for (int r = 0; r < 4; ++r) {
                int j = wave * 16 + quad * 4 + r;
                int d = dt * 16 + l16;
                float s2 = acc[r] + bf2f(Rb[j * KS + d]);
                S2[j * KS + d] = f2bf(s2);
            }
        }
    }
    __syncthreads();     // Vb/Wb/Ub/Rb dead past this point -> pool reusable

    // A1 = tril(QK^T), nA2 = -tril(Q S2^T)   (inclusive diag)
    {
        s16x8 qf = *(const s16x8*)&Qb[(wave * 16 + l16) * KS + quad * 8];
        #pragma unroll
        for (int jt = 0; jt < 4; ++jt) {
            s16x8 kf = *(const s16x8*)&Kb[(jt * 16 + l16) * KS + quad * 8];
            s16x8 sf = *(const s16x8*)&S2[(jt * 16 + l16) * KS + quad * 8];
            f32x4 z = {};
            f32x4 a1 = MFMA_BF16(qf, kf, z);
            f32x4 a2 = MFMA_BF16(qf, sf, z);
            #pragma unroll
            for (int r = 0; r < 4; ++r) {
                int t = wave * 16 + quad * 4 + r;
                int j = jt * 16 + l16;
                bool keep = (j <= t);
                A1m[t * TS + j]  = keep ? f2bf(a1[r]) : (unsigned short)0;
                nA2m[t * TS + j] = keep ? f2bf(-a2[r]) : (unsigned short)0;
            }
        }
    }
    __syncthreads();

    // O = Q Z0^T + A1m V + nA2m W ; scale exp(g); store bf16
    {
        s16x8 qf = *(const s16x8*)&Qb[(wave * 16 + l16) * KS + quad * 8];
        s16x8 p0 = *(const s16x8*)&A1m[(wave * 16 + l16) * TS + quad * 8];
        s16x8 p1 = *(const s16x8*)&A1m[(wave * 16 + l16) * TS + 32 + quad * 8];
        s16x8 m0 = *(const s16x8*)&nA2m[(wave * 16 + l16) * TS + quad * 8];
        s16x8 m1 = *(const s16x8*)&nA2m[(wave * 16 + l16) * TS + 32 + quad * 8];
        #pragma unroll
        for (int mt = 0; mt < 2; ++mt) {
            s16x8 zf = *(const s16x8*)&Z0b[(mt * 16 + l16) * ZS + quad * 8];
            s16x8 v0 = *(const s16x8*)&VT[(mt * 16 + l16) * TS + quad * 8];
            s16x8 v1 = *(const s16x8*)&VT[(mt * 16 + l16) * TS + 32 + quad * 8];
            s16x8 w0 = *(const s16x8*)&WT[(mt * 16 + l16) * TS + quad * 8];
            s16x8 w1 = *(const s16x8*)&WT[(mt * 16 + l16) * TS + 32 + quad * 8];
            f32x4 z = {};
            f32x4 acc = MFMA_BF16(qf, zf, z);
            acc = MFMA_BF16(p0, v0, acc);
            acc = MFMA_BF16(p1, v1, acc);
            acc = MFMA_BF16(m0, w0, acc);
            acc = MFMA_BF16(m1, w1, acc);
            #pragma unroll
            for (int r = 0; r < 4; ++r) {
                int t = wave * 16 + quad * 4 + r;
                int m = mt * 16 + l16;
                float e = expf(gc[t]);
                res_bf[(size_t)(row0 + t) * 256 + h * 32 + m] = f2bf(acc[r] * e);
            }
        }
    }
}

// ---------------------------------------------------------------------------
extern "C" void kernel_launch(void* const* d_in, const int* in_sizes, int n_in,
                              void* d_out, int out_size, void* d_ws, size_t ws_size,
                              hipStream_t stream)
{
    const float* x     = (const float*)d_in[0];
    const float* Wq    = (const float*)d_in[1];
    const float* Wk    = (const float*)d_in[2];
    const float* Wv    = (const float*)d_in[3];
    const float* Ww    = (const float*)d_in[4];
    const float* Wbeta = (const float*)d_in[5];
    const float* bbeta = (const float*)d_in[6];
    const float* Wg    = (const float*)d_in[7];
    const float* bg    = (const float*)d_in[8];
    const float* Wo    = (const float*)d_in[9];
    float* out = (float*)d_out;

    unsigned short* x_bf       = (unsigned short*)d_ws;           // 8,388,608
    unsigned short* stacked_bf = x_bf + (size_t)NROW * HID;       // 589,824
    unsigned short* Wo_bf      = stacked_bf + (size_t)NPAD * HID; // 131,072
    unsigned short* qb  = Wo_bf + (size_t)HID * 256;              // 4,194,304 each
    unsigned short* kb  = qb + (size_t)NROW * 256;
    unsigned short* vb  = kb + (size_t)NROW * 256;
    unsigned short* wbv = vb + (size_t)NROW * 256;
    unsigned short* ub  = wbv + (size_t)NROW * 256;
    unsigned short* rtb = ub + (size_t)NROW * 256;
    unsigned short* res_bf = rtb + (size_t)NROW * 256;
    float* betab = (float*)(res_bf + (size_t)NROW * 256);         // 131,072 f
    float* gb    = betab + (size_t)NROW * 8;
    float* D0buf = gb + (size_t)NROW * 8;                         // 2,097,152 f each
    float* Pbuf  = D0buf + (size_t)2048 * 1024;
    float* Z0buf = Pbuf + (size_t)2048 * 1024;

    // 1. casts + weight concat
    cast_bf16<<<(NROW * HID / 4 + 255) / 256, 256, 0, stream>>>(x, x_bf, NROW * HID / 4);
    cast_bf16<<<(HID * 256 / 4 + 255) / 256, 256, 0, stream>>>(Wo, Wo_bf, HID * 256 / 4);
    concat_w_bf<<<(NPAD * HID + 255) / 256, 256, 0, stream>>>(Wq, Wk, Wv, Ww, Wbeta, Wg, stacked_bf);

    // 2. projection GEMM -> head-major bf16 q/k/v/w + fp32 beta/g
    //    (1-D grid, XCD-aware bijective remap inside the kernel)
    gemm_proj<<<NROW / 128 * (NPAD / 128), 256, 0, stream>>>(
        x_bf, stacked_bf, qb, kb, vb, wbv, betab, gb, bbeta, bg);

    // 3. chunked delta-rule precompute (MFMA, pooled LDS -> 3 blocks/CU)
    chunk_pre<<<2048, 256, 0, stream>>>(kb, vb, wbv, betab, ub, rtb, D0buf, Pbuf);

    // 4. chunk-state scan (barrier-free per-wave column slices)
    scan_states<<<32, 256, 0, stream>>>(Pbuf, D0buf, Z0buf);

    // 5. Z-dependent output terms (MFMA, writes bf16 res)
    chunk_out<<<2048, 256, 0, stream>>>(qb, kb, vb, wbv, ub, rtb, Z0buf, gb, res_bf);

    // 6. output GEMM: out = res @ Wo^T (2-D grid)
    gemm_out<<<dim3(NROW / 128, HID / 128), 256, 0, stream>>>(res_bf, Wo_bf, out);
}